// Round 2
// baseline (5319.069 us; speedup 1.0000x reference)
//
#include <hip/hip_runtime.h>

// Problem constants (fixed by reference)
#define NN 20000          // nodes
#define NEDGE 320000      // edges
#define D 256             // hidden dim
#define RD 512            // router/expert input dim (2*D)
#define OD 128            // output dim
#define NEXP 8            // experts
#define NSLOT (2*NN)      // top-2 assignment slots
#define NODE_BLOCKS 79    // ceil(NN/256)
#define ASSIGN_BLOCKS 157 // ceil(2*NN/256)

// ---------------------------------------------------------------------------
// small helper kernels
// ---------------------------------------------------------------------------

// copy x into r[:, :256] (h lives in first half of r), zero edge counts
__global__ void copy_x_zero_cnt_k(const float* __restrict__ x, float* __restrict__ r,
                                  int* __restrict__ cnt) {
    int gid = blockIdx.x * 256 + threadIdx.x;          // 1,280,000 float4 units
    int n = gid >> 6;
    int c4 = gid & 63;
    if (gid < NN * (D / 4)) {
        float4 v = reinterpret_cast<const float4*>(x)[gid];
        reinterpret_cast<float4*>(r + (size_t)n * RD)[c4] = v;
    }
    if (gid < NN) cnt[gid] = 0;
}

__global__ void count_edges_k(const int* __restrict__ dst, int* __restrict__ cnt) {
    int e = blockIdx.x * 256 + threadIdx.x;
    if (e < NEDGE) atomicAdd(&cnt[dst[e]], 1);
}

__global__ void block_sums_k(const int* __restrict__ cnt, int* __restrict__ bsum) {
    __shared__ int s[256];
    int i = blockIdx.x * 256 + threadIdx.x;
    s[threadIdx.x] = (i < NN) ? cnt[i] : 0;
    __syncthreads();
    for (int off = 128; off > 0; off >>= 1) {
        if (threadIdx.x < off) s[threadIdx.x] += s[threadIdx.x + off];
        __syncthreads();
    }
    if (threadIdx.x == 0) bsum[blockIdx.x] = s[0];
}

__global__ void scan_bsums_k(int* __restrict__ bsum, int* __restrict__ row_start) {
    if (blockIdx.x == 0 && threadIdx.x == 0) {
        int acc = 0;
        for (int i = 0; i < NODE_BLOCKS; i++) { int t = bsum[i]; bsum[i] = acc; acc += t; }
        row_start[NN] = acc;   // == NEDGE
    }
}

__global__ void block_scan_k(const int* __restrict__ cnt, const int* __restrict__ bsum,
                             int* __restrict__ row_start, int* __restrict__ cur) {
    __shared__ int s[256];
    int i = blockIdx.x * 256 + threadIdx.x;
    int v = (i < NN) ? cnt[i] : 0;
    s[threadIdx.x] = v;
    __syncthreads();
    for (int off = 1; off < 256; off <<= 1) {
        int t = (threadIdx.x >= off) ? s[threadIdx.x - off] : 0;
        __syncthreads();
        s[threadIdx.x] += t;
        __syncthreads();
    }
    int excl = s[threadIdx.x] - v + bsum[blockIdx.x];
    if (i < NN) { row_start[i] = excl; cur[i] = excl; }
}

__global__ void fill_csr_k(const int* __restrict__ src, const int* __restrict__ dst,
                           int* __restrict__ cur, int* __restrict__ csr_src) {
    int e = blockIdx.x * 256 + threadIdx.x;
    if (e < NEDGE) {
        int pos = atomicAdd(&cur[dst[e]], 1);
        csr_src[pos] = src[e];
    }
}

// mean-aggregate incoming neighbors of h (= r[:, :256]) into r[:, 256:512].
// one wave per node; lane owns 4 contiguous dims (float4). Also zero ec[8].
__global__ void aggregate_k(float* __restrict__ r, const int* __restrict__ row_start,
                            const int* __restrict__ csr_src, int* __restrict__ ec) {
    if (blockIdx.x == 0 && threadIdx.x < 16) ec[threadIdx.x] = 0;
    int wid = blockIdx.x * 4 + (threadIdx.x >> 6);
    int lane = threadIdx.x & 63;
    if (wid >= NN) return;
    int beg = row_start[wid], end = row_start[wid + 1];
    float ax = 0.f, ay = 0.f, az = 0.f, aw = 0.f;
    for (int j = beg; j < end; j++) {
        int s = csr_src[j];
        float4 v = reinterpret_cast<const float4*>(r + (size_t)s * RD)[lane];
        ax += v.x; ay += v.y; az += v.z; aw += v.w;
    }
    float deg = (float)((end - beg) > 1 ? (end - beg) : 1);
    float4 o = make_float4(ax / deg, ay / deg, az / deg, aw / deg);
    reinterpret_cast<float4*>(r + (size_t)wid * RD + D)[lane] = o;
}

// hierarchical router: one wave per node, f32 throughout. NO atomics here.
// lane owns k = lane + 64*i (strided) so all global loads are coalesced.
__global__ void router_k(const float* __restrict__ r, const float* __restrict__ Wg,
                         const float* __restrict__ We, const float* __restrict__ wc,
                         int* __restrict__ node_top, float* __restrict__ node_gate,
                         float* __restrict__ conf) {
    int wid = blockIdx.x * 4 + (threadIdx.x >> 6);
    int lane = threadIdx.x & 63;
    if (wid >= NN) return;

    const float* rrow = r + (size_t)wid * RD;
    float pg[4] = {0, 0, 0, 0};
    float pe[8] = {0, 0, 0, 0, 0, 0, 0, 0};
    float pc = 0.f;
#pragma unroll
    for (int i = 0; i < 8; i++) {
        int k = lane + i * 64;
        float rv = rrow[k];                                         // coalesced
        float4 wg = *reinterpret_cast<const float4*>(Wg + (size_t)k * 4);   // 16B lane stride
        pg[0] = fmaf(rv, wg.x, pg[0]); pg[1] = fmaf(rv, wg.y, pg[1]);
        pg[2] = fmaf(rv, wg.z, pg[2]); pg[3] = fmaf(rv, wg.w, pg[3]);
        float4 w0 = *reinterpret_cast<const float4*>(We + (size_t)k * 8);
        float4 w1 = *reinterpret_cast<const float4*>(We + (size_t)k * 8 + 4);
        pe[0] = fmaf(rv, w0.x, pe[0]); pe[1] = fmaf(rv, w0.y, pe[1]);
        pe[2] = fmaf(rv, w0.z, pe[2]); pe[3] = fmaf(rv, w0.w, pe[3]);
        pe[4] = fmaf(rv, w1.x, pe[4]); pe[5] = fmaf(rv, w1.y, pe[5]);
        pe[6] = fmaf(rv, w1.z, pe[6]); pe[7] = fmaf(rv, w1.w, pe[7]);
        pc = fmaf(rv, wc[k], pc);
    }
#pragma unroll
    for (int off = 32; off > 0; off >>= 1) {
#pragma unroll
        for (int g = 0; g < 4; g++) pg[g] += __shfl_xor(pg[g], off);
#pragma unroll
        for (int g = 0; g < 8; g++) pe[g] += __shfl_xor(pe[g], off);
        pc += __shfl_xor(pc, off);
    }

    if (lane == 0) {
        float m = fmaxf(fmaxf(pg[0], pg[1]), fmaxf(pg[2], pg[3]));
        float eg[4]; float sg = 0.f;
#pragma unroll
        for (int g = 0; g < 4; g++) { eg[g] = expf(pg[g] - m); sg += eg[g]; }
        float probs[8];
#pragma unroll
        for (int g = 0; g < 4; g++) {
            float a = pe[2 * g], b = pe[2 * g + 1];
            float mm = fmaxf(a, b);
            float ea = expf(a - mm), eb = expf(b - mm);
            float inv = 1.f / (ea + eb);
            float gp = eg[g] / sg;
            probs[2 * g]     = gp * ea * inv;
            probs[2 * g + 1] = gp * eb * inv;
        }
        int i0 = 0; float v0 = probs[0];
#pragma unroll
        for (int j = 1; j < 8; j++) if (probs[j] > v0) { v0 = probs[j]; i0 = j; }
        int i1 = -1; float v1 = -1e30f;
#pragma unroll
        for (int j = 0; j < 8; j++) if (j != i0 && probs[j] > v1) { v1 = probs[j]; i1 = j; }
        float s = v0 + v1 + 1e-9f;
        node_top[2 * wid] = i0;  node_top[2 * wid + 1] = i1;
        node_gate[2 * wid] = v0 / s;  node_gate[2 * wid + 1] = v1 / s;
        conf[wid] = 1.f / (1.f + expf(-pc));
    }
}

// expert histogram over the 2*NN assignments: LDS-staged, 8 global atomics/block
__global__ void expert_hist_k(const int* __restrict__ node_top, int* __restrict__ ec) {
    __shared__ int h[NEXP];
    if (threadIdx.x < NEXP) h[threadIdx.x] = 0;
    __syncthreads();
    int i = blockIdx.x * 256 + threadIdx.x;
    if (i < NSLOT) atomicAdd(&h[node_top[i]], 1);
    __syncthreads();
    if (threadIdx.x < NEXP && h[threadIdx.x] > 0) atomicAdd(&ec[threadIdx.x], h[threadIdx.x]);
}

__global__ void expert_scan_k(const int* __restrict__ ec, int* __restrict__ es,
                              int* __restrict__ ecur) {
    if (blockIdx.x == 0 && threadIdx.x == 0) {
        int acc = 0;
        for (int e = 0; e < NEXP; e++) { es[e] = acc; acc += ec[e]; ecur[e] = 0; }
        es[NEXP] = acc;
    }
}

// block-local ranking + one range-reservation atomic per expert per block
__global__ void fill_experts_k(const int* __restrict__ node_top, const float* __restrict__ node_gate,
                               const int* __restrict__ es, int* __restrict__ ecur,
                               int* __restrict__ slot_node, float* __restrict__ slot_gate,
                               int* __restrict__ node_slot) {
    __shared__ int hcnt[NEXP], hbase[NEXP];
    int tid = threadIdx.x;
    if (tid < NEXP) hcnt[tid] = 0;
    __syncthreads();
    int i = blockIdx.x * 256 + tid;        // assignment index in [0, 2*NN)
    int e = 0, local = 0;
    bool act = (i < NSLOT);
    if (act) {
        e = node_top[i];
        local = atomicAdd(&hcnt[e], 1);    // LDS atomic: rank within block
    }
    __syncthreads();
    if (tid < NEXP) hbase[tid] = (hcnt[tid] > 0) ? atomicAdd(&ecur[tid], hcnt[tid]) : 0;
    __syncthreads();
    if (act) {
        int slot = es[e] + hbase[e] + local;
        slot_node[slot] = i >> 1;
        slot_gate[slot] = node_gate[i];
        node_slot[i] = slot;
    }
}

// h_next = relu(conf*(expout[s0]+expout[s1]) + (1-conf)*weak), written into r[:, :256]
__global__ void combine_k(const float* __restrict__ expout, const float* __restrict__ weak,
                          const float* __restrict__ conf, const int* __restrict__ node_slot,
                          float* __restrict__ r) {
    int gid = blockIdx.x * 256 + threadIdx.x;     // NN*64 float4 units
    if (gid >= NN * (D / 4)) return;
    int n = gid >> 6, c4 = gid & 63;
    int s0 = node_slot[2 * n], s1 = node_slot[2 * n + 1];
    float4 e0 = reinterpret_cast<const float4*>(expout + (size_t)s0 * D)[c4];
    float4 e1 = reinterpret_cast<const float4*>(expout + (size_t)s1 * D)[c4];
    float4 w  = reinterpret_cast<const float4*>(weak + (size_t)n * D)[c4];
    float cf = conf[n], cg = 1.f - cf;
    float4 o;
    o.x = fmaxf(cf * (e0.x + e1.x) + cg * w.x, 0.f);
    o.y = fmaxf(cf * (e0.y + e1.y) + cg * w.y, 0.f);
    o.z = fmaxf(cf * (e0.z + e1.z) + cg * w.z, 0.f);
    o.w = fmaxf(cf * (e0.w + e1.w) + cg * w.w, 0.f);
    reinterpret_cast<float4*>(r + (size_t)n * RD)[c4] = o;
}

// ---------------------------------------------------------------------------
// f32 tiled GEMM: C[M,N] = A[M,K] * B[K,N]  (B in natural [K][N] layout)
// 128x128 tile, BK=16, 256 threads, 8x8 outputs/thread.
// Double-buffered LDS: ONE barrier per K-tile; next-tile global loads issued
// before the compute phase so HBM/L2 latency hides under 1024 FMA instrs.
// MODE 0: plain, store f32 C (weak GEMM, final GEMM)
// MODE 1: expert-bucketed, A rows gathered via slot_node, +bias, relu -> C[slot]
// MODE 2: expert-bucketed, A rows are slots (hid), +bias, *gate -> C[slot]
// ---------------------------------------------------------------------------
template <int MODE>
__global__ __launch_bounds__(256, 2) void gemm_f32(
    const float* __restrict__ A, int lda,
    const float* __restrict__ B, int ldb,
    const float* __restrict__ bias,
    float* __restrict__ C, int ldc,
    const int* __restrict__ es,
    const int* __restrict__ slot_node,
    const float* __restrict__ slot_gate,
    int M, int N, int K) {
    constexpr int BM = 128, BK = 16, LDM = 132;   // LDM: padded M-stride in LDS
    constexpr int TILE = BK * LDM;
    __shared__ float sA[2 * TILE];
    __shared__ float sB[2 * TILE];

    int tid = threadIdx.x;
    int row0, valid_rows;
    if (MODE == 0) {
        row0 = blockIdx.x * BM;
        valid_rows = M - row0; if (valid_rows > BM) valid_rows = BM;
    } else {
        int bx = blockIdx.x, acc = 0, expert = -1, mt = 0;
        for (int e = 0; e < NEXP; e++) {
            int c = es[e + 1] - es[e];
            int t = (c + BM - 1) / BM;
            if (bx < acc + t) { expert = e; mt = bx - acc; row0 = es[e] + mt * BM;
                                valid_rows = c - mt * BM; if (valid_rows > BM) valid_rows = BM; break; }
            acc += t;
        }
        if (expert < 0) return;           // uniform for whole block
        B += (size_t)expert * K * ldb;
        bias += expert * D;
    }
    int ncol0 = blockIdx.y * BM;

    // staging coordinates
    int sm  = tid >> 2;            // A rows sm, sm+64
    int sk4 = (tid & 3) * 4;       // A k offset within tile
    int skB = tid >> 5;            // B rows skB, skB+8
    int sn4 = (tid & 31) * 4;      // B col offset

    // A row pointers (row gather resolved once)
    bool av0, av1;
    const float *aptr0, *aptr1;
    {
        int r0 = sm, r1 = sm + 64;
        av0 = r0 < valid_rows; av1 = r1 < valid_rows;
        int g0, g1;
        if (MODE == 1) {
            g0 = av0 ? slot_node[row0 + r0] : 0;
            g1 = av1 ? slot_node[row0 + r1] : 0;
        } else {
            g0 = row0 + (av0 ? r0 : 0);
            g1 = row0 + (av1 ? r1 : 0);
        }
        aptr0 = A + (size_t)g0 * lda + sk4;
        aptr1 = A + (size_t)g1 * lda + sk4;
    }
    const float* bptr0 = B + (size_t)skB * ldb + ncol0 + sn4;
    const float* bptr1 = bptr0 + (size_t)8 * ldb;

    const float4 f4z = make_float4(0.f, 0.f, 0.f, 0.f);
    auto stage = [&](int buf, const float4& a0, const float4& a1,
                     const float4& b0, const float4& b1) {
        float* dA = sA + buf * TILE;
        float* dB = sB + buf * TILE;
        dA[(sk4 + 0) * LDM + sm] = a0.x;
        dA[(sk4 + 1) * LDM + sm] = a0.y;
        dA[(sk4 + 2) * LDM + sm] = a0.z;
        dA[(sk4 + 3) * LDM + sm] = a0.w;
        dA[(sk4 + 0) * LDM + sm + 64] = a1.x;
        dA[(sk4 + 1) * LDM + sm + 64] = a1.y;
        dA[(sk4 + 2) * LDM + sm + 64] = a1.z;
        dA[(sk4 + 3) * LDM + sm + 64] = a1.w;
        *reinterpret_cast<float4*>(&dB[skB * LDM + sn4]) = b0;
        *reinterpret_cast<float4*>(&dB[(skB + 8) * LDM + sn4]) = b1;
    };

    float acc[2][2][4][4] = {};
    int ty4 = (tid >> 4) * 4;
    int tx4 = (tid & 15) * 4;

    // prologue: stage K-tile 0
    {
        float4 a0 = av0 ? *reinterpret_cast<const float4*>(aptr0) : f4z;
        float4 a1 = av1 ? *reinterpret_cast<const float4*>(aptr1) : f4z;
        float4 b0 = *reinterpret_cast<const float4*>(bptr0);
        float4 b1 = *reinterpret_cast<const float4*>(bptr1);
        stage(0, a0, a1, b0, b1);
    }
    __syncthreads();

    int nk = K / BK;
    for (int t = 0; t < nk; t++) {
        int cur = t & 1;
        bool more = (t + 1 < nk);
        float4 a0 = f4z, a1 = f4z, b0 = f4z, b1 = f4z;
        if (more) {
            int k0 = (t + 1) * BK;
            a0 = av0 ? *reinterpret_cast<const float4*>(aptr0 + k0) : f4z;
            a1 = av1 ? *reinterpret_cast<const float4*>(aptr1 + k0) : f4z;
            b0 = *reinterpret_cast<const float4*>(bptr0 + (size_t)k0 * ldb);
            b1 = *reinterpret_cast<const float4*>(bptr1 + (size_t)k0 * ldb);
        }
        const float* cA = sA + cur * TILE;
        const float* cB = sB + cur * TILE;
#pragma unroll
        for (int k = 0; k < BK; k++) {
            float4 alo = *reinterpret_cast<const float4*>(&cA[k * LDM + ty4]);
            float4 ahi = *reinterpret_cast<const float4*>(&cA[k * LDM + 64 + ty4]);
            float4 blo = *reinterpret_cast<const float4*>(&cB[k * LDM + tx4]);
            float4 bhi = *reinterpret_cast<const float4*>(&cB[k * LDM + 64 + tx4]);
            float al[4] = {alo.x, alo.y, alo.z, alo.w};
            float ah[4] = {ahi.x, ahi.y, ahi.z, ahi.w};
            float bl[4] = {blo.x, blo.y, blo.z, blo.w};
            float bh[4] = {bhi.x, bhi.y, bhi.z, bhi.w};
#pragma unroll
            for (int i = 0; i < 4; i++)
#pragma unroll
                for (int j = 0; j < 4; j++) {
                    acc[0][0][i][j] = fmaf(al[i], bl[j], acc[0][0][i][j]);
                    acc[0][1][i][j] = fmaf(al[i], bh[j], acc[0][1][i][j]);
                    acc[1][0][i][j] = fmaf(ah[i], bl[j], acc[1][0][i][j]);
                    acc[1][1][i][j] = fmaf(ah[i], bh[j], acc[1][1][i][j]);
                }
        }
        if (more) {
            stage(cur ^ 1, a0, a1, b0, b1);
            __syncthreads();
        }
    }

    // epilogue
#pragma unroll
    for (int ri = 0; ri < 2; ri++) {
#pragma unroll
        for (int i = 0; i < 4; i++) {
            int lr = ri * 64 + ty4 + i;
            if (lr >= valid_rows) continue;
#pragma unroll
            for (int ci = 0; ci < 2; ci++) {
                int cb = ncol0 + ci * 64 + tx4;
                float4 v = make_float4(acc[ri][ci][i][0], acc[ri][ci][i][1],
                                       acc[ri][ci][i][2], acc[ri][ci][i][3]);
                if (MODE == 0) {
                    int gr = row0 + lr;
                    *reinterpret_cast<float4*>(&C[(size_t)gr * ldc + cb]) = v;
                } else if (MODE == 1) {
                    int slot = row0 + lr;
                    v.x = fmaxf(v.x + bias[cb + 0], 0.f);
                    v.y = fmaxf(v.y + bias[cb + 1], 0.f);
                    v.z = fmaxf(v.z + bias[cb + 2], 0.f);
                    v.w = fmaxf(v.w + bias[cb + 3], 0.f);
                    *reinterpret_cast<float4*>(&C[(size_t)slot * ldc + cb]) = v;
                } else {
                    int slot = row0 + lr;
                    float g = slot_gate[slot];
                    v.x = (v.x + bias[cb + 0]) * g;
                    v.y = (v.y + bias[cb + 1]) * g;
                    v.z = (v.z + bias[cb + 2]) * g;
                    v.w = (v.w + bias[cb + 3]) * g;
                    *reinterpret_cast<float4*>(&C[(size_t)slot * ldc + cb]) = v;
                }
            }
        }
    }
}

// ---------------------------------------------------------------------------
extern "C" void kernel_launch(void* const* d_in, const int* in_sizes, int n_in,
                              void* d_out, int out_size, void* d_ws, size_t ws_size,
                              hipStream_t stream) {
    (void)in_sizes; (void)n_in; (void)out_size; (void)ws_size;
    const float* x    = (const float*)d_in[0];
    const int*   ei   = (const int*)d_in[1];
    const float* Wg   = (const float*)d_in[2];
    const float* We   = (const float*)d_in[3];
    const float* Ww   = (const float*)d_in[4];
    const float* W1   = (const float*)d_in[5];
    const float* b1   = (const float*)d_in[6];
    const float* W2   = (const float*)d_in[7];
    const float* b2   = (const float*)d_in[8];
    const float* wc   = (const float*)d_in[9];
    const float* Wout = (const float*)d_in[10];
    float* out = (float*)d_out;

    char* p = (char*)d_ws;
    auto alloc = [&](size_t bytes) -> char* {
        char* q = p; p += (bytes + 255) & ~(size_t)255; return q;
    };
    int*   cnt       = (int*)alloc((size_t)NN * 4);
    int*   row_start = (int*)alloc((size_t)(NN + 1) * 4);
    int*   cur       = (int*)alloc((size_t)NN * 4);
    int*   bsum      = (int*)alloc(128 * 4);
    int*   csr_src   = (int*)alloc((size_t)NEDGE * 4);
    float* r         = (float*)alloc((size_t)NN * RD * 4);
    float* hid       = (float*)alloc((size_t)NSLOT * D * 4);
    float* expout    = (float*)alloc((size_t)NSLOT * D * 4);
    float* weak      = (float*)alloc((size_t)NN * D * 4);
    float* conf      = (float*)alloc((size_t)NN * 4);
    int*   node_top  = (int*)alloc((size_t)2 * NN * 4);
    float* node_gate = (float*)alloc((size_t)2 * NN * 4);
    int*   node_slot = (int*)alloc((size_t)2 * NN * 4);
    int*   slot_node = (int*)alloc((size_t)NSLOT * 4);
    float* slot_gate = (float*)alloc((size_t)NSLOT * 4);
    int*   ec        = (int*)alloc(64 * 4);
    int*   es        = (int*)alloc(64 * 4);
    int*   ecur      = (int*)alloc(64 * 4);

    const int* srcp = ei;
    const int* dstp = ei + NEDGE;
    const int EB = (NEDGE + 255) / 256;

    // graph prep (once per launch)
    copy_x_zero_cnt_k<<<5000, 256, 0, stream>>>(x, r, cnt);
    count_edges_k<<<EB, 256, 0, stream>>>(dstp, cnt);
    block_sums_k<<<NODE_BLOCKS, 256, 0, stream>>>(cnt, bsum);
    scan_bsums_k<<<1, 64, 0, stream>>>(bsum, row_start);
    block_scan_k<<<NODE_BLOCKS, 256, 0, stream>>>(cnt, bsum, row_start, cur);
    fill_csr_k<<<EB, 256, 0, stream>>>(srcp, dstp, cur, csr_src);

    dim3 g_weak(157, 2), g_exp(320, 2), g_fin(157, 1);
    for (int l = 0; l < 3; l++) {
        aggregate_k<<<5000, 256, 0, stream>>>(r, row_start, csr_src, ec);
        router_k<<<5000, 256, 0, stream>>>(r,
            Wg + (size_t)l * RD * 4, We + (size_t)l * RD * 8, wc + (size_t)l * RD,
            node_top, node_gate, conf);
        expert_hist_k<<<ASSIGN_BLOCKS, 256, 0, stream>>>(node_top, ec);
        expert_scan_k<<<1, 64, 0, stream>>>(ec, es, ecur);
        fill_experts_k<<<ASSIGN_BLOCKS, 256, 0, stream>>>(node_top, node_gate, es, ecur,
                                                          slot_node, slot_gate, node_slot);
        // weak = r @ Ww[l]
        gemm_f32<0><<<g_weak, 256, 0, stream>>>(r, RD, Ww + (size_t)l * RD * D, D,
                                                nullptr, weak, D,
                                                nullptr, nullptr, nullptr, NN, D, RD);
        // hid[slot] = relu(r[node] @ W1[l][e] + b1[l][e])
        gemm_f32<1><<<g_exp, 256, 0, stream>>>(r, RD, W1 + (size_t)l * NEXP * RD * D, D,
                                               b1 + (size_t)l * NEXP * D, hid, D,
                                               es, slot_node, slot_gate, 0, D, RD);
        // expout[slot] = (hid[slot] @ W2[l][e] + b2[l][e]) * gate[slot]
        gemm_f32<2><<<g_exp, 256, 0, stream>>>(hid, D, W2 + (size_t)l * NEXP * D * D, D,
                                               b2 + (size_t)l * NEXP * D, expout, D,
                                               es, slot_node, slot_gate, 0, D, D);
        combine_k<<<5000, 256, 0, stream>>>(expout, weak, conf, node_slot, r);
    }
    // out = h @ Wout
    gemm_f32<0><<<g_fin, 256, 0, stream>>>(r, RD, Wout, OD, nullptr, out, OD,
                                           nullptr, nullptr, nullptr, NN, OD, D);
}

// Round 3
// 1288.717 us; speedup vs baseline: 4.1274x; 4.1274x over previous
//
#include <hip/hip_runtime.h>

// Problem constants (fixed by reference)
#define NN 20000          // nodes
#define NEDGE 320000      // edges
#define D 256             // hidden dim
#define RD 512            // router/expert input dim (2*D)
#define OD 128            // output dim
#define NEXP 8            // experts
#define NSLOT (2*NN)      // top-2 assignment slots
#define NODE_BLOCKS 79    // ceil(NN/256)
#define ASSIGN_BLOCKS 157 // ceil(2*NN/256)

// ---------------------------------------------------------------------------
// small helper kernels
// ---------------------------------------------------------------------------

// copy x into r[:, :256] (h lives in first half of r), zero edge counts
__global__ void copy_x_zero_cnt_k(const float* __restrict__ x, float* __restrict__ r,
                                  int* __restrict__ cnt) {
    int gid = blockIdx.x * 256 + threadIdx.x;          // 1,280,000 float4 units
    int n = gid >> 6;
    int c4 = gid & 63;
    if (gid < NN * (D / 4)) {
        float4 v = reinterpret_cast<const float4*>(x)[gid];
        reinterpret_cast<float4*>(r + (size_t)n * RD)[c4] = v;
    }
    if (gid < NN) cnt[gid] = 0;
}

__global__ void count_edges_k(const int* __restrict__ dst, int* __restrict__ cnt) {
    int e = blockIdx.x * 256 + threadIdx.x;
    if (e < NEDGE) atomicAdd(&cnt[dst[e]], 1);
}

__global__ void block_sums_k(const int* __restrict__ cnt, int* __restrict__ bsum) {
    __shared__ int s[256];
    int i = blockIdx.x * 256 + threadIdx.x;
    s[threadIdx.x] = (i < NN) ? cnt[i] : 0;
    __syncthreads();
    for (int off = 128; off > 0; off >>= 1) {
        if (threadIdx.x < off) s[threadIdx.x] += s[threadIdx.x + off];
        __syncthreads();
    }
    if (threadIdx.x == 0) bsum[blockIdx.x] = s[0];
}

__global__ void scan_bsums_k(int* __restrict__ bsum, int* __restrict__ row_start) {
    if (blockIdx.x == 0 && threadIdx.x == 0) {
        int acc = 0;
        for (int i = 0; i < NODE_BLOCKS; i++) { int t = bsum[i]; bsum[i] = acc; acc += t; }
        row_start[NN] = acc;   // == NEDGE
    }
}

__global__ void block_scan_k(const int* __restrict__ cnt, const int* __restrict__ bsum,
                             int* __restrict__ row_start, int* __restrict__ cur) {
    __shared__ int s[256];
    int i = blockIdx.x * 256 + threadIdx.x;
    int v = (i < NN) ? cnt[i] : 0;
    s[threadIdx.x] = v;
    __syncthreads();
    for (int off = 1; off < 256; off <<= 1) {
        int t = (threadIdx.x >= off) ? s[threadIdx.x - off] : 0;
        __syncthreads();
        s[threadIdx.x] += t;
        __syncthreads();
    }
    int excl = s[threadIdx.x] - v + bsum[blockIdx.x];
    if (i < NN) { row_start[i] = excl; cur[i] = excl; }
}

__global__ void fill_csr_k(const int* __restrict__ src, const int* __restrict__ dst,
                           int* __restrict__ cur, int* __restrict__ csr_src) {
    int e = blockIdx.x * 256 + threadIdx.x;
    if (e < NEDGE) {
        int pos = atomicAdd(&cur[dst[e]], 1);
        csr_src[pos] = src[e];
    }
}

// mean-aggregate incoming neighbors of h (= r[:, :256]) into r[:, 256:512].
// one wave per node; lane owns 4 contiguous dims (float4). Also zero ec[8].
__global__ void aggregate_k(float* __restrict__ r, const int* __restrict__ row_start,
                            const int* __restrict__ csr_src, int* __restrict__ ec) {
    if (blockIdx.x == 0 && threadIdx.x < 16) ec[threadIdx.x] = 0;
    int wid = blockIdx.x * 4 + (threadIdx.x >> 6);
    int lane = threadIdx.x & 63;
    if (wid >= NN) return;
    int beg = row_start[wid], end = row_start[wid + 1];
    float ax = 0.f, ay = 0.f, az = 0.f, aw = 0.f;
    for (int j = beg; j < end; j++) {
        int s = csr_src[j];
        float4 v = reinterpret_cast<const float4*>(r + (size_t)s * RD)[lane];
        ax += v.x; ay += v.y; az += v.z; aw += v.w;
    }
    float deg = (float)((end - beg) > 1 ? (end - beg) : 1);
    float4 o = make_float4(ax / deg, ay / deg, az / deg, aw / deg);
    reinterpret_cast<float4*>(r + (size_t)wid * RD + D)[lane] = o;
}

// hierarchical router: one wave per node, f32 throughout. NO atomics here.
// lane owns k = lane + 64*i (strided) so all global loads are coalesced.
__global__ void router_k(const float* __restrict__ r, const float* __restrict__ Wg,
                         const float* __restrict__ We, const float* __restrict__ wc,
                         int* __restrict__ node_top, float* __restrict__ node_gate,
                         float* __restrict__ conf) {
    int wid = blockIdx.x * 4 + (threadIdx.x >> 6);
    int lane = threadIdx.x & 63;
    if (wid >= NN) return;

    const float* rrow = r + (size_t)wid * RD;
    float pg[4] = {0, 0, 0, 0};
    float pe[8] = {0, 0, 0, 0, 0, 0, 0, 0};
    float pc = 0.f;
#pragma unroll
    for (int i = 0; i < 8; i++) {
        int k = lane + i * 64;
        float rv = rrow[k];                                         // coalesced
        float4 wg = *reinterpret_cast<const float4*>(Wg + (size_t)k * 4);   // 16B lane stride
        pg[0] = fmaf(rv, wg.x, pg[0]); pg[1] = fmaf(rv, wg.y, pg[1]);
        pg[2] = fmaf(rv, wg.z, pg[2]); pg[3] = fmaf(rv, wg.w, pg[3]);
        float4 w0 = *reinterpret_cast<const float4*>(We + (size_t)k * 8);
        float4 w1 = *reinterpret_cast<const float4*>(We + (size_t)k * 8 + 4);
        pe[0] = fmaf(rv, w0.x, pe[0]); pe[1] = fmaf(rv, w0.y, pe[1]);
        pe[2] = fmaf(rv, w0.z, pe[2]); pe[3] = fmaf(rv, w0.w, pe[3]);
        pe[4] = fmaf(rv, w1.x, pe[4]); pe[5] = fmaf(rv, w1.y, pe[5]);
        pe[6] = fmaf(rv, w1.z, pe[6]); pe[7] = fmaf(rv, w1.w, pe[7]);
        pc = fmaf(rv, wc[k], pc);
    }
#pragma unroll
    for (int off = 32; off > 0; off >>= 1) {
#pragma unroll
        for (int g = 0; g < 4; g++) pg[g] += __shfl_xor(pg[g], off);
#pragma unroll
        for (int g = 0; g < 8; g++) pe[g] += __shfl_xor(pe[g], off);
        pc += __shfl_xor(pc, off);
    }

    if (lane == 0) {
        float m = fmaxf(fmaxf(pg[0], pg[1]), fmaxf(pg[2], pg[3]));
        float eg[4]; float sg = 0.f;
#pragma unroll
        for (int g = 0; g < 4; g++) { eg[g] = expf(pg[g] - m); sg += eg[g]; }
        float probs[8];
#pragma unroll
        for (int g = 0; g < 4; g++) {
            float a = pe[2 * g], b = pe[2 * g + 1];
            float mm = fmaxf(a, b);
            float ea = expf(a - mm), eb = expf(b - mm);
            float inv = 1.f / (ea + eb);
            float gp = eg[g] / sg;
            probs[2 * g]     = gp * ea * inv;
            probs[2 * g + 1] = gp * eb * inv;
        }
        int i0 = 0; float v0 = probs[0];
#pragma unroll
        for (int j = 1; j < 8; j++) if (probs[j] > v0) { v0 = probs[j]; i0 = j; }
        int i1 = -1; float v1 = -1e30f;
#pragma unroll
        for (int j = 0; j < 8; j++) if (j != i0 && probs[j] > v1) { v1 = probs[j]; i1 = j; }
        float s = v0 + v1 + 1e-9f;
        node_top[2 * wid] = i0;  node_top[2 * wid + 1] = i1;
        node_gate[2 * wid] = v0 / s;  node_gate[2 * wid + 1] = v1 / s;
        conf[wid] = 1.f / (1.f + expf(-pc));
    }
}

// expert histogram over the 2*NN assignments: LDS-staged, 8 global atomics/block
__global__ void expert_hist_k(const int* __restrict__ node_top, int* __restrict__ ec) {
    __shared__ int h[NEXP];
    if (threadIdx.x < NEXP) h[threadIdx.x] = 0;
    __syncthreads();
    int i = blockIdx.x * 256 + threadIdx.x;
    if (i < NSLOT) atomicAdd(&h[node_top[i]], 1);
    __syncthreads();
    if (threadIdx.x < NEXP && h[threadIdx.x] > 0) atomicAdd(&ec[threadIdx.x], h[threadIdx.x]);
}

__global__ void expert_scan_k(const int* __restrict__ ec, int* __restrict__ es,
                              int* __restrict__ ecur) {
    if (blockIdx.x == 0 && threadIdx.x == 0) {
        int acc = 0;
        for (int e = 0; e < NEXP; e++) { es[e] = acc; acc += ec[e]; ecur[e] = 0; }
        es[NEXP] = acc;
    }
}

// block-local ranking + one range-reservation atomic per expert per block
__global__ void fill_experts_k(const int* __restrict__ node_top, const float* __restrict__ node_gate,
                               const int* __restrict__ es, int* __restrict__ ecur,
                               int* __restrict__ slot_node, float* __restrict__ slot_gate,
                               int* __restrict__ node_slot) {
    __shared__ int hcnt[NEXP], hbase[NEXP];
    int tid = threadIdx.x;
    if (tid < NEXP) hcnt[tid] = 0;
    __syncthreads();
    int i = blockIdx.x * 256 + tid;        // assignment index in [0, 2*NN)
    int e = 0, local = 0;
    bool act = (i < NSLOT);
    if (act) {
        e = node_top[i];
        local = atomicAdd(&hcnt[e], 1);    // LDS atomic: rank within block
    }
    __syncthreads();
    if (tid < NEXP) hbase[tid] = (hcnt[tid] > 0) ? atomicAdd(&ecur[tid], hcnt[tid]) : 0;
    __syncthreads();
    if (act) {
        int slot = es[e] + hbase[e] + local;
        slot_node[slot] = i >> 1;
        slot_gate[slot] = node_gate[i];
        node_slot[i] = slot;
    }
}

// h_next = relu(conf*(expout[s0]+expout[s1]) + (1-conf)*weak), written into r[:, :256]
__global__ void combine_k(const float* __restrict__ expout, const float* __restrict__ weak,
                          const float* __restrict__ conf, const int* __restrict__ node_slot,
                          float* __restrict__ r) {
    int gid = blockIdx.x * 256 + threadIdx.x;     // NN*64 float4 units
    if (gid >= NN * (D / 4)) return;
    int n = gid >> 6, c4 = gid & 63;
    int s0 = node_slot[2 * n], s1 = node_slot[2 * n + 1];
    float4 e0 = reinterpret_cast<const float4*>(expout + (size_t)s0 * D)[c4];
    float4 e1 = reinterpret_cast<const float4*>(expout + (size_t)s1 * D)[c4];
    float4 w  = reinterpret_cast<const float4*>(weak + (size_t)n * D)[c4];
    float cf = conf[n], cg = 1.f - cf;
    float4 o;
    o.x = fmaxf(cf * (e0.x + e1.x) + cg * w.x, 0.f);
    o.y = fmaxf(cf * (e0.y + e1.y) + cg * w.y, 0.f);
    o.z = fmaxf(cf * (e0.z + e1.z) + cg * w.z, 0.f);
    o.w = fmaxf(cf * (e0.w + e1.w) + cg * w.w, 0.f);
    reinterpret_cast<float4*>(r + (size_t)n * RD)[c4] = o;
}

// ---------------------------------------------------------------------------
// f32 tiled GEMM: C[M,N] = A[M,K] * B[K,N]  (B in natural [K][N] layout)
// 128x128 tile, BK=16, 256 threads, 8x8 outputs/thread. Single LDS buffer,
// 2 barriers per K-tile (round-1 structure: known spill-free).
// MODE 0: plain, store f32 C (weak GEMM, final GEMM)
// MODE 1: expert-bucketed, A rows gathered via slot_node, +bias, relu -> C[slot]
// MODE 2: expert-bucketed, A rows are slots (hid), +bias, *gate -> C[slot]
// ---------------------------------------------------------------------------
template <int MODE>
__global__ __launch_bounds__(256, 2) void gemm_f32(
    const float* __restrict__ A, int lda,
    const float* __restrict__ B, int ldb,
    const float* __restrict__ bias,
    float* __restrict__ C, int ldc,
    const int* __restrict__ es,
    const int* __restrict__ slot_node,
    const float* __restrict__ slot_gate,
    int M, int N, int K) {
    constexpr int BM = 128, BK = 16, LDM = 132;   // LDM: padded M-stride in LDS
    __shared__ float sA[BK * LDM];
    __shared__ float sB[BK * LDM];

    int tid = threadIdx.x;
    int row0, valid_rows;
    if (MODE == 0) {
        row0 = blockIdx.x * BM;
        valid_rows = M - row0; if (valid_rows > BM) valid_rows = BM;
    } else {
        int bx = blockIdx.x, acc = 0, expert = -1, mt = 0;
        for (int e = 0; e < NEXP; e++) {
            int c = es[e + 1] - es[e];
            int t = (c + BM - 1) / BM;
            if (bx < acc + t) { expert = e; mt = bx - acc; row0 = es[e] + mt * BM;
                                valid_rows = c - mt * BM; if (valid_rows > BM) valid_rows = BM; break; }
            acc += t;
        }
        if (expert < 0) return;           // uniform for whole block
        B += (size_t)expert * K * ldb;
        bias += expert * D;
    }
    int ncol0 = blockIdx.y * BM;

    // staging coordinates
    int sm  = tid >> 2;            // A rows sm, sm+64
    int sk4 = (tid & 3) * 4;       // A k offset within tile
    int skB = tid >> 5;            // B rows skB, skB+8
    int sn4 = (tid & 31) * 4;      // B col offset

    // A row pointers (row gather resolved once)
    bool av0, av1;
    const float *aptr0, *aptr1;
    {
        int r0 = sm, r1 = sm + 64;
        av0 = r0 < valid_rows; av1 = r1 < valid_rows;
        int g0, g1;
        if (MODE == 1) {
            g0 = av0 ? slot_node[row0 + r0] : 0;
            g1 = av1 ? slot_node[row0 + r1] : 0;
        } else {
            g0 = row0 + (av0 ? r0 : 0);
            g1 = row0 + (av1 ? r1 : 0);
        }
        aptr0 = A + (size_t)g0 * lda + sk4;
        aptr1 = A + (size_t)g1 * lda + sk4;
    }
    const float* bptr0 = B + (size_t)skB * ldb + ncol0 + sn4;
    const float* bptr1 = bptr0 + (size_t)8 * ldb;

    float acc[2][2][4][4] = {};
    int ty4 = (tid >> 4) * 4;
    int tx4 = (tid & 15) * 4;

    for (int k0 = 0; k0 < K; k0 += BK) {
        float4 a0 = av0 ? *reinterpret_cast<const float4*>(aptr0 + k0) : make_float4(0, 0, 0, 0);
        float4 a1 = av1 ? *reinterpret_cast<const float4*>(aptr1 + k0) : make_float4(0, 0, 0, 0);
        float4 b0 = *reinterpret_cast<const float4*>(bptr0 + (size_t)k0 * ldb);
        float4 b1 = *reinterpret_cast<const float4*>(bptr1 + (size_t)k0 * ldb);
        __syncthreads();
        // A transposed into sA[k][m]
        sA[(sk4 + 0) * LDM + sm] = a0.x;
        sA[(sk4 + 1) * LDM + sm] = a0.y;
        sA[(sk4 + 2) * LDM + sm] = a0.z;
        sA[(sk4 + 3) * LDM + sm] = a0.w;
        sA[(sk4 + 0) * LDM + sm + 64] = a1.x;
        sA[(sk4 + 1) * LDM + sm + 64] = a1.y;
        sA[(sk4 + 2) * LDM + sm + 64] = a1.z;
        sA[(sk4 + 3) * LDM + sm + 64] = a1.w;
        // B natural into sB[k][n]
        *reinterpret_cast<float4*>(&sB[skB * LDM + sn4]) = b0;
        *reinterpret_cast<float4*>(&sB[(skB + 8) * LDM + sn4]) = b1;
        __syncthreads();
#pragma unroll
        for (int k = 0; k < BK; k++) {
            float4 alo = *reinterpret_cast<const float4*>(&sA[k * LDM + ty4]);
            float4 ahi = *reinterpret_cast<const float4*>(&sA[k * LDM + 64 + ty4]);
            float4 blo = *reinterpret_cast<const float4*>(&sB[k * LDM + tx4]);
            float4 bhi = *reinterpret_cast<const float4*>(&sB[k * LDM + 64 + tx4]);
            float al[4] = {alo.x, alo.y, alo.z, alo.w};
            float ah[4] = {ahi.x, ahi.y, ahi.z, ahi.w};
            float bl[4] = {blo.x, blo.y, blo.z, blo.w};
            float bh[4] = {bhi.x, bhi.y, bhi.z, bhi.w};
#pragma unroll
            for (int i = 0; i < 4; i++)
#pragma unroll
                for (int j = 0; j < 4; j++) {
                    acc[0][0][i][j] = fmaf(al[i], bl[j], acc[0][0][i][j]);
                    acc[0][1][i][j] = fmaf(al[i], bh[j], acc[0][1][i][j]);
                    acc[1][0][i][j] = fmaf(ah[i], bl[j], acc[1][0][i][j]);
                    acc[1][1][i][j] = fmaf(ah[i], bh[j], acc[1][1][i][j]);
                }
        }
    }

    // epilogue
#pragma unroll
    for (int ri = 0; ri < 2; ri++) {
#pragma unroll
        for (int i = 0; i < 4; i++) {
            int lr = ri * 64 + ty4 + i;
            if (lr >= valid_rows) continue;
#pragma unroll
            for (int ci = 0; ci < 2; ci++) {
                int cb = ncol0 + ci * 64 + tx4;
                float4 v = make_float4(acc[ri][ci][i][0], acc[ri][ci][i][1],
                                       acc[ri][ci][i][2], acc[ri][ci][i][3]);
                if (MODE == 0) {
                    int gr = row0 + lr;
                    *reinterpret_cast<float4*>(&C[(size_t)gr * ldc + cb]) = v;
                } else if (MODE == 1) {
                    int slot = row0 + lr;
                    v.x = fmaxf(v.x + bias[cb + 0], 0.f);
                    v.y = fmaxf(v.y + bias[cb + 1], 0.f);
                    v.z = fmaxf(v.z + bias[cb + 2], 0.f);
                    v.w = fmaxf(v.w + bias[cb + 3], 0.f);
                    *reinterpret_cast<float4*>(&C[(size_t)slot * ldc + cb]) = v;
                } else {
                    int slot = row0 + lr;
                    float g = slot_gate[slot];
                    v.x = (v.x + bias[cb + 0]) * g;
                    v.y = (v.y + bias[cb + 1]) * g;
                    v.z = (v.z + bias[cb + 2]) * g;
                    v.w = (v.w + bias[cb + 3]) * g;
                    *reinterpret_cast<float4*>(&C[(size_t)slot * ldc + cb]) = v;
                }
            }
        }
    }
}

// ---------------------------------------------------------------------------
extern "C" void kernel_launch(void* const* d_in, const int* in_sizes, int n_in,
                              void* d_out, int out_size, void* d_ws, size_t ws_size,
                              hipStream_t stream) {
    (void)in_sizes; (void)n_in; (void)out_size; (void)ws_size;
    const float* x    = (const float*)d_in[0];
    const int*   ei   = (const int*)d_in[1];
    const float* Wg   = (const float*)d_in[2];
    const float* We   = (const float*)d_in[3];
    const float* Ww   = (const float*)d_in[4];
    const float* W1   = (const float*)d_in[5];
    const float* b1   = (const float*)d_in[6];
    const float* W2   = (const float*)d_in[7];
    const float* b2   = (const float*)d_in[8];
    const float* wc   = (const float*)d_in[9];
    const float* Wout = (const float*)d_in[10];
    float* out = (float*)d_out;

    char* p = (char*)d_ws;
    auto alloc = [&](size_t bytes) -> char* {
        char* q = p; p += (bytes + 255) & ~(size_t)255; return q;
    };
    int*   cnt       = (int*)alloc((size_t)NN * 4);
    int*   row_start = (int*)alloc((size_t)(NN + 1) * 4);
    int*   cur       = (int*)alloc((size_t)NN * 4);
    int*   bsum      = (int*)alloc(128 * 4);
    int*   csr_src   = (int*)alloc((size_t)NEDGE * 4);
    float* r         = (float*)alloc((size_t)NN * RD * 4);
    float* hid       = (float*)alloc((size_t)NSLOT * D * 4);
    float* expout    = (float*)alloc((size_t)NSLOT * D * 4);
    float* weak      = (float*)alloc((size_t)NN * D * 4);
    float* conf      = (float*)alloc((size_t)NN * 4);
    int*   node_top  = (int*)alloc((size_t)2 * NN * 4);
    float* node_gate = (float*)alloc((size_t)2 * NN * 4);
    int*   node_slot = (int*)alloc((size_t)2 * NN * 4);
    int*   slot_node = (int*)alloc((size_t)NSLOT * 4);
    float* slot_gate = (float*)alloc((size_t)NSLOT * 4);
    int*   ec        = (int*)alloc(64 * 4);
    int*   es        = (int*)alloc(64 * 4);
    int*   ecur      = (int*)alloc(64 * 4);

    const int* srcp = ei;
    const int* dstp = ei + NEDGE;
    const int EB = (NEDGE + 255) / 256;

    // graph prep (once per launch)
    copy_x_zero_cnt_k<<<5000, 256, 0, stream>>>(x, r, cnt);
    count_edges_k<<<EB, 256, 0, stream>>>(dstp, cnt);
    block_sums_k<<<NODE_BLOCKS, 256, 0, stream>>>(cnt, bsum);
    scan_bsums_k<<<1, 64, 0, stream>>>(bsum, row_start);
    block_scan_k<<<NODE_BLOCKS, 256, 0, stream>>>(cnt, bsum, row_start, cur);
    fill_csr_k<<<EB, 256, 0, stream>>>(srcp, dstp, cur, csr_src);

    dim3 g_weak(157, 2), g_exp(320, 2), g_fin(157, 1);
    for (int l = 0; l < 3; l++) {
        aggregate_k<<<5000, 256, 0, stream>>>(r, row_start, csr_src, ec);
        router_k<<<5000, 256, 0, stream>>>(r,
            Wg + (size_t)l * RD * 4, We + (size_t)l * RD * 8, wc + (size_t)l * RD,
            node_top, node_gate, conf);
        expert_hist_k<<<ASSIGN_BLOCKS, 256, 0, stream>>>(node_top, ec);
        expert_scan_k<<<1, 64, 0, stream>>>(ec, es, ecur);
        fill_experts_k<<<ASSIGN_BLOCKS, 256, 0, stream>>>(node_top, node_gate, es, ecur,
                                                          slot_node, slot_gate, node_slot);
        // weak = r @ Ww[l]
        gemm_f32<0><<<g_weak, 256, 0, stream>>>(r, RD, Ww + (size_t)l * RD * D, D,
                                                nullptr, weak, D,
                                                nullptr, nullptr, nullptr, NN, D, RD);
        // hid[slot] = relu(r[node] @ W1[l][e] + b1[l][e])
        gemm_f32<1><<<g_exp, 256, 0, stream>>>(r, RD, W1 + (size_t)l * NEXP * RD * D, D,
                                               b1 + (size_t)l * NEXP * D, hid, D,
                                               es, slot_node, slot_gate, 0, D, RD);
        // expout[slot] = (hid[slot] @ W2[l][e] + b2[l][e]) * gate[slot]
        gemm_f32<2><<<g_exp, 256, 0, stream>>>(hid, D, W2 + (size_t)l * NEXP * D * D, D,
                                               b2 + (size_t)l * NEXP * D, expout, D,
                                               es, slot_node, slot_gate, 0, D, D);
        combine_k<<<5000, 256, 0, stream>>>(expout, weak, conf, node_slot, r);
    }
    // out = h @ Wout
    gemm_f32<0><<<g_fin, 256, 0, stream>>>(r, RD, Wout, OD, nullptr, out, OD,
                                           nullptr, nullptr, nullptr, NN, OD, D);
}

// Round 4
// 958.589 us; speedup vs baseline: 5.5488x; 1.3444x over previous
//
#include <hip/hip_runtime.h>

// Problem constants (fixed by reference)
#define NN 20000          // nodes
#define NEDGE 320000      // edges
#define D 256             // hidden dim
#define RD 512            // router/expert input dim (2*D)
#define OD 128            // output dim
#define NEXP 8            // experts
#define NSLOT (2*NN)      // top-2 assignment slots
#define NODE_BLOCKS 79    // ceil(NN/256)
#define ASSIGN_BLOCKS 157 // ceil(2*NN/256)

#define LDK 40            // padded K-stride of LDS tiles (bf16 elems; 80 B rows)
#define PL (128 * LDK)    // one bf16 plane in LDS (elems)

typedef unsigned short u16;
typedef __attribute__((ext_vector_type(8))) short short8v;
typedef __attribute__((ext_vector_type(16))) float f32x16;

// exact 3-way bf16 split: v == H + M + L (bit-truncation; 24 mantissa bits)
__device__ __forceinline__ void split1(float v, u16& h, u16& m, u16& l) {
    unsigned b = __float_as_uint(v);
    h = (u16)(b >> 16);
    float fh = __uint_as_float(b & 0xffff0000u);
    float r1 = v - fh;
    unsigned b1 = __float_as_uint(r1);
    m = (u16)(b1 >> 16);
    float fm = __uint_as_float(b1 & 0xffff0000u);
    float r2 = r1 - fm;
    l = (u16)(__float_as_uint(r2) >> 16);
}

__device__ __forceinline__ void split8(const float4& x, const float4& y,
                                       short8v& h, short8v& m, short8v& l) {
    float v[8] = {x.x, x.y, x.z, x.w, y.x, y.y, y.z, y.w};
#pragma unroll
    for (int i = 0; i < 8; i++) {
        u16 hh, mm, ll;
        split1(v[i], hh, mm, ll);
        h[i] = (short)hh; m[i] = (short)mm; l[i] = (short)ll;
    }
}

// ---------------------------------------------------------------------------
// small helper kernels (unchanged from round 3 where possible)
// ---------------------------------------------------------------------------

__global__ void copy_x_zero_cnt_k(const float* __restrict__ x, float* __restrict__ r,
                                  int* __restrict__ cnt) {
    int gid = blockIdx.x * 256 + threadIdx.x;
    int n = gid >> 6;
    int c4 = gid & 63;
    if (gid < NN * (D / 4)) {
        float4 v = reinterpret_cast<const float4*>(x)[gid];
        reinterpret_cast<float4*>(r + (size_t)n * RD)[c4] = v;
    }
    if (gid < NN) cnt[gid] = 0;
}

__global__ void count_edges_k(const int* __restrict__ dst, int* __restrict__ cnt) {
    int e = blockIdx.x * 256 + threadIdx.x;
    if (e < NEDGE) atomicAdd(&cnt[dst[e]], 1);
}

__global__ void block_sums_k(const int* __restrict__ cnt, int* __restrict__ bsum) {
    __shared__ int s[256];
    int i = blockIdx.x * 256 + threadIdx.x;
    s[threadIdx.x] = (i < NN) ? cnt[i] : 0;
    __syncthreads();
    for (int off = 128; off > 0; off >>= 1) {
        if (threadIdx.x < off) s[threadIdx.x] += s[threadIdx.x + off];
        __syncthreads();
    }
    if (threadIdx.x == 0) bsum[blockIdx.x] = s[0];
}

__global__ void scan_bsums_k(int* __restrict__ bsum, int* __restrict__ row_start) {
    if (blockIdx.x == 0 && threadIdx.x == 0) {
        int acc = 0;
        for (int i = 0; i < NODE_BLOCKS; i++) { int t = bsum[i]; bsum[i] = acc; acc += t; }
        row_start[NN] = acc;
    }
}

__global__ void block_scan_k(const int* __restrict__ cnt, const int* __restrict__ bsum,
                             int* __restrict__ row_start, int* __restrict__ cur) {
    __shared__ int s[256];
    int i = blockIdx.x * 256 + threadIdx.x;
    int v = (i < NN) ? cnt[i] : 0;
    s[threadIdx.x] = v;
    __syncthreads();
    for (int off = 1; off < 256; off <<= 1) {
        int t = (threadIdx.x >= off) ? s[threadIdx.x - off] : 0;
        __syncthreads();
        s[threadIdx.x] += t;
        __syncthreads();
    }
    int excl = s[threadIdx.x] - v + bsum[blockIdx.x];
    if (i < NN) { row_start[i] = excl; cur[i] = excl; }
}

__global__ void fill_csr_k(const int* __restrict__ src, const int* __restrict__ dst,
                           int* __restrict__ cur, int* __restrict__ csr_src) {
    int e = blockIdx.x * 256 + threadIdx.x;
    if (e < NEDGE) {
        int pos = atomicAdd(&cur[dst[e]], 1);
        csr_src[pos] = src[e];
    }
}

__global__ void aggregate_k(float* __restrict__ r, const int* __restrict__ row_start,
                            const int* __restrict__ csr_src, int* __restrict__ ec) {
    if (blockIdx.x == 0 && threadIdx.x < 16) ec[threadIdx.x] = 0;
    int wid = blockIdx.x * 4 + (threadIdx.x >> 6);
    int lane = threadIdx.x & 63;
    if (wid >= NN) return;
    int beg = row_start[wid], end = row_start[wid + 1];
    float ax = 0.f, ay = 0.f, az = 0.f, aw = 0.f;
    for (int j = beg; j < end; j++) {
        int s = csr_src[j];
        float4 v = reinterpret_cast<const float4*>(r + (size_t)s * RD)[lane];
        ax += v.x; ay += v.y; az += v.z; aw += v.w;
    }
    float deg = (float)((end - beg) > 1 ? (end - beg) : 1);
    float4 o = make_float4(ax / deg, ay / deg, az / deg, aw / deg);
    reinterpret_cast<float4*>(r + (size_t)wid * RD + D)[lane] = o;
}

__global__ void router_k(const float* __restrict__ r, const float* __restrict__ Wg,
                         const float* __restrict__ We, const float* __restrict__ wc,
                         int* __restrict__ node_top, float* __restrict__ node_gate,
                         float* __restrict__ conf) {
    int wid = blockIdx.x * 4 + (threadIdx.x >> 6);
    int lane = threadIdx.x & 63;
    if (wid >= NN) return;

    const float* rrow = r + (size_t)wid * RD;
    float pg[4] = {0, 0, 0, 0};
    float pe[8] = {0, 0, 0, 0, 0, 0, 0, 0};
    float pc = 0.f;
#pragma unroll
    for (int i = 0; i < 8; i++) {
        int k = lane + i * 64;
        float rv = rrow[k];
        float4 wg = *reinterpret_cast<const float4*>(Wg + (size_t)k * 4);
        pg[0] = fmaf(rv, wg.x, pg[0]); pg[1] = fmaf(rv, wg.y, pg[1]);
        pg[2] = fmaf(rv, wg.z, pg[2]); pg[3] = fmaf(rv, wg.w, pg[3]);
        float4 w0 = *reinterpret_cast<const float4*>(We + (size_t)k * 8);
        float4 w1 = *reinterpret_cast<const float4*>(We + (size_t)k * 8 + 4);
        pe[0] = fmaf(rv, w0.x, pe[0]); pe[1] = fmaf(rv, w0.y, pe[1]);
        pe[2] = fmaf(rv, w0.z, pe[2]); pe[3] = fmaf(rv, w0.w, pe[3]);
        pe[4] = fmaf(rv, w1.x, pe[4]); pe[5] = fmaf(rv, w1.y, pe[5]);
        pe[6] = fmaf(rv, w1.z, pe[6]); pe[7] = fmaf(rv, w1.w, pe[7]);
        pc = fmaf(rv, wc[k], pc);
    }
#pragma unroll
    for (int off = 32; off > 0; off >>= 1) {
#pragma unroll
        for (int g = 0; g < 4; g++) pg[g] += __shfl_xor(pg[g], off);
#pragma unroll
        for (int g = 0; g < 8; g++) pe[g] += __shfl_xor(pe[g], off);
        pc += __shfl_xor(pc, off);
    }

    if (lane == 0) {
        float m = fmaxf(fmaxf(pg[0], pg[1]), fmaxf(pg[2], pg[3]));
        float eg[4]; float sg = 0.f;
#pragma unroll
        for (int g = 0; g < 4; g++) { eg[g] = expf(pg[g] - m); sg += eg[g]; }
        float probs[8];
#pragma unroll
        for (int g = 0; g < 4; g++) {
            float a = pe[2 * g], b = pe[2 * g + 1];
            float mm = fmaxf(a, b);
            float ea = expf(a - mm), eb = expf(b - mm);
            float inv = 1.f / (ea + eb);
            float gp = eg[g] / sg;
            probs[2 * g]     = gp * ea * inv;
            probs[2 * g + 1] = gp * eb * inv;
        }
        int i0 = 0; float v0 = probs[0];
#pragma unroll
        for (int j = 1; j < 8; j++) if (probs[j] > v0) { v0 = probs[j]; i0 = j; }
        int i1 = -1; float v1 = -1e30f;
#pragma unroll
        for (int j = 0; j < 8; j++) if (j != i0 && probs[j] > v1) { v1 = probs[j]; i1 = j; }
        float s = v0 + v1 + 1e-9f;
        node_top[2 * wid] = i0;  node_top[2 * wid + 1] = i1;
        node_gate[2 * wid] = v0 / s;  node_gate[2 * wid + 1] = v1 / s;
        conf[wid] = 1.f / (1.f + expf(-pc));
    }
}

__global__ void expert_hist_k(const int* __restrict__ node_top, int* __restrict__ ec) {
    __shared__ int h[NEXP];
    if (threadIdx.x < NEXP) h[threadIdx.x] = 0;
    __syncthreads();
    int i = blockIdx.x * 256 + threadIdx.x;
    if (i < NSLOT) atomicAdd(&h[node_top[i]], 1);
    __syncthreads();
    if (threadIdx.x < NEXP && h[threadIdx.x] > 0) atomicAdd(&ec[threadIdx.x], h[threadIdx.x]);
}

__global__ void expert_scan_k(const int* __restrict__ ec, int* __restrict__ es,
                              int* __restrict__ ecur) {
    if (blockIdx.x == 0 && threadIdx.x == 0) {
        int acc = 0;
        for (int e = 0; e < NEXP; e++) { es[e] = acc; acc += ec[e]; ecur[e] = 0; }
        es[NEXP] = acc;
    }
}

__global__ void fill_experts_k(const int* __restrict__ node_top, const float* __restrict__ node_gate,
                               const int* __restrict__ es, int* __restrict__ ecur,
                               int* __restrict__ slot_node, float* __restrict__ slot_gate,
                               int* __restrict__ node_slot) {
    __shared__ int hcnt[NEXP], hbase[NEXP];
    int tid = threadIdx.x;
    if (tid < NEXP) hcnt[tid] = 0;
    __syncthreads();
    int i = blockIdx.x * 256 + tid;
    int e = 0, local = 0;
    bool act = (i < NSLOT);
    if (act) {
        e = node_top[i];
        local = atomicAdd(&hcnt[e], 1);
    }
    __syncthreads();
    if (tid < NEXP) hbase[tid] = (hcnt[tid] > 0) ? atomicAdd(&ecur[tid], hcnt[tid]) : 0;
    __syncthreads();
    if (act) {
        int slot = es[e] + hbase[e] + local;
        slot_node[slot] = i >> 1;
        slot_gate[slot] = node_gate[i];
        node_slot[i] = slot;
    }
}

__global__ void combine_k(const float* __restrict__ expout, const float* __restrict__ weak,
                          const float* __restrict__ conf, const int* __restrict__ node_slot,
                          float* __restrict__ r) {
    int gid = blockIdx.x * 256 + threadIdx.x;
    if (gid >= NN * (D / 4)) return;
    int n = gid >> 6, c4 = gid & 63;
    int s0 = node_slot[2 * n], s1 = node_slot[2 * n + 1];
    float4 e0 = reinterpret_cast<const float4*>(expout + (size_t)s0 * D)[c4];
    float4 e1 = reinterpret_cast<const float4*>(expout + (size_t)s1 * D)[c4];
    float4 w  = reinterpret_cast<const float4*>(weak + (size_t)n * D)[c4];
    float cf = conf[n], cg = 1.f - cf;
    float4 o;
    o.x = fmaxf(cf * (e0.x + e1.x) + cg * w.x, 0.f);
    o.y = fmaxf(cf * (e0.y + e1.y) + cg * w.y, 0.f);
    o.z = fmaxf(cf * (e0.z + e1.z) + cg * w.z, 0.f);
    o.w = fmaxf(cf * (e0.w + e1.w) + cg * w.w, 0.f);
    reinterpret_cast<float4*>(r + (size_t)n * RD)[c4] = o;
}

// ---------------------------------------------------------------------------
// weight transpose + bf16x3 split: src = nm matrices [K][N] f32 (row-major),
// dst planes [nm][N][K] bf16. K,N multiples of 64.
// ---------------------------------------------------------------------------
__global__ void tsplit_k(const float* __restrict__ src, u16* __restrict__ dH,
                         u16* __restrict__ dM, u16* __restrict__ dL, int K, int N) {
    __shared__ float t[64][65];
    int mat = blockIdx.z;
    int k0 = blockIdx.x * 64, n0 = blockIdx.y * 64;
    const float* s = src + (size_t)mat * K * N;
#pragma unroll
    for (int i = 0; i < 16; i++) {
        int idx = threadIdx.x + i * 256;
        int kk = idx >> 6, nn = idx & 63;
        t[kk][nn] = s[(size_t)(k0 + kk) * N + n0 + nn];
    }
    __syncthreads();
    size_t base = (size_t)mat * N * K;
#pragma unroll
    for (int i = 0; i < 16; i++) {
        int idx = threadIdx.x + i * 256;
        int nn = idx >> 6, kk = idx & 63;
        float v = t[kk][nn];
        u16 h, m, l; split1(v, h, m, l);
        size_t o = base + (size_t)(n0 + nn) * K + k0 + kk;
        dH[o] = h; dM[o] = m; dL[o] = l;
    }
}

// ---------------------------------------------------------------------------
// bf16x3 split MFMA GEMM: C[M,N] = A[M,K] * B[K,N], f32-accurate (~2^-25).
// A: f32, split on the fly during LDS staging. B: pre-split bf16 planes [N][K].
// 128x128 block tile, 4 waves of 64x64 (2x2 frags of 32x32x16), BK=32.
// MODE 0: plain rows; MODE 1: rows gathered via slot_node, +bias, relu;
// MODE 2: rows are slots, +bias, *gate.
// ---------------------------------------------------------------------------
template <int MODE>
__global__ __launch_bounds__(256, 2) void gemm_mfma(
    const float* __restrict__ A, int lda,
    const u16* __restrict__ BH, const u16* __restrict__ BM,
    const u16* __restrict__ BL,
    const float* __restrict__ bias,
    float* __restrict__ C, int ldc,
    const int* __restrict__ es,
    const int* __restrict__ slot_node,
    const float* __restrict__ slot_gate,
    int M, int N, int K) {
    __shared__ u16 sA[3 * PL];
    __shared__ u16 sB[3 * PL];

    int tid = threadIdx.x;
    int row0, valid_rows;
    if (MODE == 0) {
        row0 = blockIdx.x * 128;
        valid_rows = M - row0; if (valid_rows > 128) valid_rows = 128;
    } else {
        int bx = blockIdx.x, acc0 = 0, expert = -1, mt = 0;
        row0 = 0; valid_rows = 0;
        for (int e = 0; e < NEXP; e++) {
            int c = es[e + 1] - es[e];
            int t = (c + 127) >> 7;
            if (bx < acc0 + t) {
                expert = e; mt = bx - acc0; row0 = es[e] + (mt << 7);
                valid_rows = c - (mt << 7); if (valid_rows > 128) valid_rows = 128;
                break;
            }
            acc0 += t;
        }
        if (expert < 0) return;
        size_t bo = (size_t)expert * N * K;
        BH += bo; BM += bo; BL += bo;
        bias += expert * D;
    }
    int ncol0 = blockIdx.y * 128;

    // staging coords: thread covers A/B rows (sr, sr+64), k-chunk ksf..ksf+8
    int sr = tid >> 2;
    int ksf = (tid & 3) * 8;

    int g0, g1;
    {
        int i0 = row0 + sr, i1 = i0 + 64;
        if (MODE == 1) {
            i0 = i0 < NSLOT ? i0 : NSLOT - 1;
            i1 = i1 < NSLOT ? i1 : NSLOT - 1;
            g0 = slot_node[i0]; g1 = slot_node[i1];
        } else {
            int cap = M - 1;
            g0 = i0 < M ? i0 : cap;
            g1 = i1 < M ? i1 : cap;
        }
    }
    const float* pA0 = A + (size_t)g0 * lda + ksf;
    const float* pA1 = A + (size_t)g1 * lda + ksf;
    size_t bro0 = (size_t)(ncol0 + sr) * K + ksf;
    size_t bro1 = bro0 + (size_t)64 * K;

    // fragment coords
    int lane = tid & 63;
    int wr = ((tid >> 7) & 1) * 64;   // wave row offset
    int wc = ((tid >> 6) & 1) * 64;   // wave col offset
    int fl = lane & 31;
    int fh8 = (lane >> 5) * 8;

    f32x16 acc[2][2] = {};

    int aoff = sr * LDK + ksf;

    for (int kt = 0; kt < K; kt += 32) {
        float4 a00 = *reinterpret_cast<const float4*>(pA0 + kt);
        float4 a01 = *reinterpret_cast<const float4*>(pA0 + kt + 4);
        float4 a10 = *reinterpret_cast<const float4*>(pA1 + kt);
        float4 a11 = *reinterpret_cast<const float4*>(pA1 + kt + 4);
        short8v b0h = *reinterpret_cast<const short8v*>(BH + bro0 + kt);
        short8v b0m = *reinterpret_cast<const short8v*>(BM + bro0 + kt);
        short8v b0l = *reinterpret_cast<const short8v*>(BL + bro0 + kt);
        short8v b1h = *reinterpret_cast<const short8v*>(BH + bro1 + kt);
        short8v b1m = *reinterpret_cast<const short8v*>(BM + bro1 + kt);
        short8v b1l = *reinterpret_cast<const short8v*>(BL + bro1 + kt);
        __syncthreads();
        {
            short8v h, m, l;
            split8(a00, a01, h, m, l);
            *reinterpret_cast<short8v*>(&sA[0 * PL + aoff]) = h;
            *reinterpret_cast<short8v*>(&sA[1 * PL + aoff]) = m;
            *reinterpret_cast<short8v*>(&sA[2 * PL + aoff]) = l;
            split8(a10, a11, h, m, l);
            *reinterpret_cast<short8v*>(&sA[0 * PL + aoff + 64 * LDK]) = h;
            *reinterpret_cast<short8v*>(&sA[1 * PL + aoff + 64 * LDK]) = m;
            *reinterpret_cast<short8v*>(&sA[2 * PL + aoff + 64 * LDK]) = l;
            *reinterpret_cast<short8v*>(&sB[0 * PL + aoff]) = b0h;
            *reinterpret_cast<short8v*>(&sB[1 * PL + aoff]) = b0m;
            *reinterpret_cast<short8v*>(&sB[2 * PL + aoff]) = b0l;
            *reinterpret_cast<short8v*>(&sB[0 * PL + aoff + 64 * LDK]) = b1h;
            *reinterpret_cast<short8v*>(&sB[1 * PL + aoff + 64 * LDK]) = b1m;
            *reinterpret_cast<short8v*>(&sB[2 * PL + aoff + 64 * LDK]) = b1l;
        }
        __syncthreads();
#pragma unroll
        for (int kk = 0; kk < 2; kk++) {
            int ko = kk * 16 + fh8;
            const u16* A0 = sA + (wr + fl) * LDK + ko;
            const u16* A1 = A0 + 32 * LDK;
            const u16* B0 = sB + (wc + fl) * LDK + ko;
            const u16* B1 = B0 + 32 * LDK;
            short8v aH0 = *reinterpret_cast<const short8v*>(A0);
            short8v aM0 = *reinterpret_cast<const short8v*>(A0 + PL);
            short8v aL0 = *reinterpret_cast<const short8v*>(A0 + 2 * PL);
            short8v aH1 = *reinterpret_cast<const short8v*>(A1);
            short8v aM1 = *reinterpret_cast<const short8v*>(A1 + PL);
            short8v aL1 = *reinterpret_cast<const short8v*>(A1 + 2 * PL);
            short8v bH0 = *reinterpret_cast<const short8v*>(B0);
            short8v bM0 = *reinterpret_cast<const short8v*>(B0 + PL);
            short8v bL0 = *reinterpret_cast<const short8v*>(B0 + 2 * PL);
            short8v bH1 = *reinterpret_cast<const short8v*>(B1);
            short8v bM1 = *reinterpret_cast<const short8v*>(B1 + PL);
            short8v bL1 = *reinterpret_cast<const short8v*>(B1 + 2 * PL);
#define MFMA_ACC(d, a, b) d = __builtin_amdgcn_mfma_f32_32x32x16_bf16(a, b, d, 0, 0, 0)
            MFMA_ACC(acc[0][0], aH0, bH0); MFMA_ACC(acc[0][0], aH0, bM0);
            MFMA_ACC(acc[0][0], aM0, bH0); MFMA_ACC(acc[0][0], aH0, bL0);
            MFMA_ACC(acc[0][0], aM0, bM0); MFMA_ACC(acc[0][0], aL0, bH0);
            MFMA_ACC(acc[0][1], aH0, bH1); MFMA_ACC(acc[0][1], aH0, bM1);
            MFMA_ACC(acc[0][1], aM0, bH1); MFMA_ACC(acc[0][1], aH0, bL1);
            MFMA_ACC(acc[0][1], aM0, bM1); MFMA_ACC(acc[0][1], aL0, bH1);
            MFMA_ACC(acc[1][0], aH1, bH0); MFMA_ACC(acc[1][0], aH1, bM0);
            MFMA_ACC(acc[1][0], aM1, bH0); MFMA_ACC(acc[1][0], aH1, bL0);
            MFMA_ACC(acc[1][0], aM1, bM0); MFMA_ACC(acc[1][0], aL1, bH0);
            MFMA_ACC(acc[1][1], aH1, bH1); MFMA_ACC(acc[1][1], aH1, bM1);
            MFMA_ACC(acc[1][1], aM1, bH1); MFMA_ACC(acc[1][1], aH1, bL1);
            MFMA_ACC(acc[1][1], aM1, bM1); MFMA_ACC(acc[1][1], aL1, bH1);
#undef MFMA_ACC
        }
    }

    // epilogue: C/D layout col=lane&31, row=(reg&3)+8*(reg>>2)+4*(lane>>5)
    int fh = lane >> 5;
#pragma unroll
    for (int i = 0; i < 2; i++) {
#pragma unroll
        for (int j = 0; j < 2; j++) {
            int colg = ncol0 + wc + j * 32 + fl;
            float bv = (MODE != 0) ? bias[colg] : 0.f;
#pragma unroll
            for (int rg = 0; rg < 16; rg++) {
                int lrow = wr + i * 32 + (rg & 3) + 8 * (rg >> 2) + 4 * fh;
                if (lrow >= valid_rows) continue;
                int grow = row0 + lrow;
                float v = acc[i][j][rg] + bv;
                if (MODE == 1) {
                    v = fmaxf(v, 0.f);
                } else if (MODE == 2) {
                    v *= slot_gate[grow];
                }
                C[(size_t)grow * ldc + colg] = v;
            }
        }
    }
}

// ---------------------------------------------------------------------------
extern "C" void kernel_launch(void* const* d_in, const int* in_sizes, int n_in,
                              void* d_out, int out_size, void* d_ws, size_t ws_size,
                              hipStream_t stream) {
    (void)in_sizes; (void)n_in; (void)out_size; (void)ws_size;
    const float* x    = (const float*)d_in[0];
    const int*   ei   = (const int*)d_in[1];
    const float* Wg   = (const float*)d_in[2];
    const float* We   = (const float*)d_in[3];
    const float* Ww   = (const float*)d_in[4];
    const float* W1   = (const float*)d_in[5];
    const float* b1   = (const float*)d_in[6];
    const float* W2   = (const float*)d_in[7];
    const float* b2   = (const float*)d_in[8];
    const float* wcp  = (const float*)d_in[9];
    const float* Wout = (const float*)d_in[10];
    float* out = (float*)d_out;

    char* p = (char*)d_ws;
    auto alloc = [&](size_t bytes) -> char* {
        char* q = p; p += (bytes + 255) & ~(size_t)255; return q;
    };
    int*   cnt       = (int*)alloc((size_t)NN * 4);
    int*   row_start = (int*)alloc((size_t)(NN + 1) * 4);
    int*   cur       = (int*)alloc((size_t)NN * 4);
    int*   bsum      = (int*)alloc(128 * 4);
    int*   csr_src   = (int*)alloc((size_t)NEDGE * 4);
    float* r         = (float*)alloc((size_t)NN * RD * 4);
    float* hid       = (float*)alloc((size_t)NSLOT * D * 4);   // weak aliases rows 0..NN-1 after GEMM2
    float* expout    = (float*)alloc((size_t)NSLOT * D * 4);
    float* conf      = (float*)alloc((size_t)NN * 4);
    int*   node_top  = (int*)alloc((size_t)2 * NN * 4);
    float* node_gate = (float*)alloc((size_t)2 * NN * 4);
    int*   node_slot = (int*)alloc((size_t)2 * NN * 4);
    int*   slot_node = (int*)alloc((size_t)NSLOT * 4);
    float* slot_gate = (float*)alloc((size_t)NSLOT * 4);
    int*   ec        = (int*)alloc(64 * 4);
    int*   es        = (int*)alloc(64 * 4);
    int*   ecur      = (int*)alloc(64 * 4);
    // per-layer weight planes (transposed [N][K] bf16 x 3)
    u16* w1tH = (u16*)alloc((size_t)NEXP * D * RD * 2);
    u16* w1tM = (u16*)alloc((size_t)NEXP * D * RD * 2);
    u16* w1tL = (u16*)alloc((size_t)NEXP * D * RD * 2);
    u16* w2tH = (u16*)alloc((size_t)NEXP * D * D * 2);
    u16* w2tM = (u16*)alloc((size_t)NEXP * D * D * 2);
    u16* w2tL = (u16*)alloc((size_t)NEXP * D * D * 2);
    u16* wwtH = (u16*)alloc((size_t)D * RD * 2);
    u16* wwtM = (u16*)alloc((size_t)D * RD * 2);
    u16* wwtL = (u16*)alloc((size_t)D * RD * 2);
    u16* wotH = (u16*)alloc((size_t)OD * D * 2);
    u16* wotM = (u16*)alloc((size_t)OD * D * 2);
    u16* wotL = (u16*)alloc((size_t)OD * D * 2);
    float* weak = hid;   // alias: hid is dead when weak GEMM runs

    const int* srcp = ei;
    const int* dstp = ei + NEDGE;
    const int EB = (NEDGE + 255) / 256;

    // graph prep (once per launch)
    copy_x_zero_cnt_k<<<5000, 256, 0, stream>>>(x, r, cnt);
    count_edges_k<<<EB, 256, 0, stream>>>(dstp, cnt);
    block_sums_k<<<NODE_BLOCKS, 256, 0, stream>>>(cnt, bsum);
    scan_bsums_k<<<1, 64, 0, stream>>>(bsum, row_start);
    block_scan_k<<<NODE_BLOCKS, 256, 0, stream>>>(cnt, bsum, row_start, cur);
    fill_csr_k<<<EB, 256, 0, stream>>>(srcp, dstp, cur, csr_src);
    // Wout planes (once)
    tsplit_k<<<dim3(4, 2, 1), 256, 0, stream>>>(Wout, wotH, wotM, wotL, D, OD);

    for (int l = 0; l < 3; l++) {
        // weight planes for this layer
        tsplit_k<<<dim3(8, 4, 8), 256, 0, stream>>>(W1 + (size_t)l * NEXP * RD * D,
                                                    w1tH, w1tM, w1tL, RD, D);
        tsplit_k<<<dim3(4, 4, 8), 256, 0, stream>>>(W2 + (size_t)l * NEXP * D * D,
                                                    w2tH, w2tM, w2tL, D, D);
        tsplit_k<<<dim3(8, 4, 1), 256, 0, stream>>>(Ww + (size_t)l * RD * D,
                                                    wwtH, wwtM, wwtL, RD, D);
        aggregate_k<<<5000, 256, 0, stream>>>(r, row_start, csr_src, ec);
        router_k<<<5000, 256, 0, stream>>>(r,
            Wg + (size_t)l * RD * 4, We + (size_t)l * RD * 8, wcp + (size_t)l * RD,
            node_top, node_gate, conf);
        expert_hist_k<<<ASSIGN_BLOCKS, 256, 0, stream>>>(node_top, ec);
        expert_scan_k<<<1, 64, 0, stream>>>(ec, es, ecur);
        fill_experts_k<<<ASSIGN_BLOCKS, 256, 0, stream>>>(node_top, node_gate, es, ecur,
                                                          slot_node, slot_gate, node_slot);
        // hid[slot] = relu(r[node] @ W1[e] + b1[e])
        gemm_mfma<1><<<dim3(320, 2), 256, 0, stream>>>(r, RD, w1tH, w1tM, w1tL,
            b1 + (size_t)l * NEXP * D, hid, D, es, slot_node, slot_gate, NSLOT, D, RD);
        // expout[slot] = (hid[slot] @ W2[e] + b2[e]) * gate[slot]
        gemm_mfma<2><<<dim3(320, 2), 256, 0, stream>>>(hid, D, w2tH, w2tM, w2tL,
            b2 + (size_t)l * NEXP * D, expout, D, es, slot_node, slot_gate, NSLOT, D, D);
        // weak = r @ Ww  (writes over hid rows 0..NN-1, safe: hid consumed)
        gemm_mfma<0><<<dim3(157, 2), 256, 0, stream>>>(r, RD, wwtH, wwtM, wwtL,
            nullptr, weak, D, nullptr, nullptr, nullptr, NN, D, RD);
        combine_k<<<5000, 256, 0, stream>>>(expout, weak, conf, node_slot, r);
    }
    // out = h @ Wout  (h = r[:, :256], so K=256 over lda=512)
    gemm_mfma<0><<<dim3(157, 1), 256, 0, stream>>>(r, RD, wotH, wotM, wotL,
        nullptr, out, OD, nullptr, nullptr, nullptr, NN, OD, D);
}

// Round 5
// 840.841 us; speedup vs baseline: 6.3259x; 1.1400x over previous
//
#include <hip/hip_runtime.h>

// Problem constants (fixed by reference)
#define NN 20000          // nodes
#define NEDGE 320000      // edges
#define D 256             // hidden dim
#define RD 512            // router/expert input dim (2*D)
#define OD 128            // output dim
#define NEXP 8            // experts
#define NSLOT (2*NN)      // top-2 assignment slots
#define NODE_BLOCKS 79    // ceil(NN/256)
#define ASSIGN_BLOCKS 157 // ceil(2*NN/256)

typedef unsigned short u16;
typedef __attribute__((ext_vector_type(8))) short short8v;
typedef __attribute__((ext_vector_type(16))) float f32x16;

// exact 3-way bf16 split: v == H + M + L (bit-truncation; 24 mantissa bits)
__device__ __forceinline__ void split1(float v, u16& h, u16& m, u16& l) {
    unsigned b = __float_as_uint(v);
    h = (u16)(b >> 16);
    float fh = __uint_as_float(b & 0xffff0000u);
    float r1 = v - fh;
    unsigned b1 = __float_as_uint(r1);
    m = (u16)(b1 >> 16);
    float fm = __uint_as_float(b1 & 0xffff0000u);
    float r2 = r1 - fm;
    l = (u16)(__float_as_uint(r2) >> 16);
}

__device__ __forceinline__ void split8(const float4& x, const float4& y,
                                       short8v& h, short8v& m, short8v& l) {
    float v[8] = {x.x, x.y, x.z, x.w, y.x, y.y, y.z, y.w};
#pragma unroll
    for (int i = 0; i < 8; i++) {
        u16 hh, mm, ll;
        split1(v[i], hh, mm, ll);
        h[i] = (short)hh; m[i] = (short)mm; l[i] = (short)ll;
    }
}

// ---------------------------------------------------------------------------
// small helper kernels
// ---------------------------------------------------------------------------

__global__ void copy_x_zero_cnt_k(const float* __restrict__ x, float* __restrict__ r,
                                  int* __restrict__ cnt) {
    int gid = blockIdx.x * 256 + threadIdx.x;
    int n = gid >> 6;
    int c4 = gid & 63;
    if (gid < NN * (D / 4)) {
        float4 v = reinterpret_cast<const float4*>(x)[gid];
        reinterpret_cast<float4*>(r + (size_t)n * RD)[c4] = v;
    }
    if (gid < NN) cnt[gid] = 0;
}

__global__ void count_edges_k(const int* __restrict__ dst, int* __restrict__ cnt) {
    int e = blockIdx.x * 256 + threadIdx.x;
    if (e < NEDGE) atomicAdd(&cnt[dst[e]], 1);
}

__global__ void block_sums_k(const int* __restrict__ cnt, int* __restrict__ bsum) {
    __shared__ int s[256];
    int i = blockIdx.x * 256 + threadIdx.x;
    s[threadIdx.x] = (i < NN) ? cnt[i] : 0;
    __syncthreads();
    for (int off = 128; off > 0; off >>= 1) {
        if (threadIdx.x < off) s[threadIdx.x] += s[threadIdx.x + off];
        __syncthreads();
    }
    if (threadIdx.x == 0) bsum[blockIdx.x] = s[0];
}

__global__ void scan_bsums_k(int* __restrict__ bsum, int* __restrict__ row_start) {
    if (blockIdx.x == 0 && threadIdx.x == 0) {
        int acc = 0;
        for (int i = 0; i < NODE_BLOCKS; i++) { int t = bsum[i]; bsum[i] = acc; acc += t; }
        row_start[NN] = acc;
    }
}

__global__ void block_scan_k(const int* __restrict__ cnt, const int* __restrict__ bsum,
                             int* __restrict__ row_start, int* __restrict__ cur) {
    __shared__ int s[256];
    int i = blockIdx.x * 256 + threadIdx.x;
    int v = (i < NN) ? cnt[i] : 0;
    s[threadIdx.x] = v;
    __syncthreads();
    for (int off = 1; off < 256; off <<= 1) {
        int t = (threadIdx.x >= off) ? s[threadIdx.x - off] : 0;
        __syncthreads();
        s[threadIdx.x] += t;
        __syncthreads();
    }
    int excl = s[threadIdx.x] - v + bsum[blockIdx.x];
    if (i < NN) { row_start[i] = excl; cur[i] = excl; }
}

__global__ void fill_csr_k(const int* __restrict__ src, const int* __restrict__ dst,
                           int* __restrict__ cur, int* __restrict__ csr_src) {
    int e = blockIdx.x * 256 + threadIdx.x;
    if (e < NEDGE) {
        int pos = atomicAdd(&cur[dst[e]], 1);
        csr_src[pos] = src[e];
    }
}

__global__ void aggregate_k(float* __restrict__ r, const int* __restrict__ row_start,
                            const int* __restrict__ csr_src, int* __restrict__ ec) {
    if (blockIdx.x == 0 && threadIdx.x < 16) ec[threadIdx.x] = 0;
    int wid = blockIdx.x * 4 + (threadIdx.x >> 6);
    int lane = threadIdx.x & 63;
    if (wid >= NN) return;
    int beg = row_start[wid], end = row_start[wid + 1];
    float ax = 0.f, ay = 0.f, az = 0.f, aw = 0.f;
    for (int j = beg; j < end; j++) {
        int s = csr_src[j];
        float4 v = reinterpret_cast<const float4*>(r + (size_t)s * RD)[lane];
        ax += v.x; ay += v.y; az += v.z; aw += v.w;
    }
    float deg = (float)((end - beg) > 1 ? (end - beg) : 1);
    float4 o = make_float4(ax / deg, ay / deg, az / deg, aw / deg);
    reinterpret_cast<float4*>(r + (size_t)wid * RD + D)[lane] = o;
}

__global__ void router_k(const float* __restrict__ r, const float* __restrict__ Wg,
                         const float* __restrict__ We, const float* __restrict__ wc,
                         int* __restrict__ node_top, float* __restrict__ node_gate,
                         float* __restrict__ conf) {
    int wid = blockIdx.x * 4 + (threadIdx.x >> 6);
    int lane = threadIdx.x & 63;
    if (wid >= NN) return;

    const float* rrow = r + (size_t)wid * RD;
    float pg[4] = {0, 0, 0, 0};
    float pe[8] = {0, 0, 0, 0, 0, 0, 0, 0};
    float pc = 0.f;
#pragma unroll
    for (int i = 0; i < 8; i++) {
        int k = lane + i * 64;
        float rv = rrow[k];
        float4 wg = *reinterpret_cast<const float4*>(Wg + (size_t)k * 4);
        pg[0] = fmaf(rv, wg.x, pg[0]); pg[1] = fmaf(rv, wg.y, pg[1]);
        pg[2] = fmaf(rv, wg.z, pg[2]); pg[3] = fmaf(rv, wg.w, pg[3]);
        float4 w0 = *reinterpret_cast<const float4*>(We + (size_t)k * 8);
        float4 w1 = *reinterpret_cast<const float4*>(We + (size_t)k * 8 + 4);
        pe[0] = fmaf(rv, w0.x, pe[0]); pe[1] = fmaf(rv, w0.y, pe[1]);
        pe[2] = fmaf(rv, w0.z, pe[2]); pe[3] = fmaf(rv, w0.w, pe[3]);
        pe[4] = fmaf(rv, w1.x, pe[4]); pe[5] = fmaf(rv, w1.y, pe[5]);
        pe[6] = fmaf(rv, w1.z, pe[6]); pe[7] = fmaf(rv, w1.w, pe[7]);
        pc = fmaf(rv, wc[k], pc);
    }
#pragma unroll
    for (int off = 32; off > 0; off >>= 1) {
#pragma unroll
        for (int g = 0; g < 4; g++) pg[g] += __shfl_xor(pg[g], off);
#pragma unroll
        for (int g = 0; g < 8; g++) pe[g] += __shfl_xor(pe[g], off);
        pc += __shfl_xor(pc, off);
    }

    if (lane == 0) {
        float m = fmaxf(fmaxf(pg[0], pg[1]), fmaxf(pg[2], pg[3]));
        float eg[4]; float sg = 0.f;
#pragma unroll
        for (int g = 0; g < 4; g++) { eg[g] = expf(pg[g] - m); sg += eg[g]; }
        float probs[8];
#pragma unroll
        for (int g = 0; g < 4; g++) {
            float a = pe[2 * g], b = pe[2 * g + 1];
            float mm = fmaxf(a, b);
            float ea = expf(a - mm), eb = expf(b - mm);
            float inv = 1.f / (ea + eb);
            float gp = eg[g] / sg;
            probs[2 * g]     = gp * ea * inv;
            probs[2 * g + 1] = gp * eb * inv;
        }
        int i0 = 0; float v0 = probs[0];
#pragma unroll
        for (int j = 1; j < 8; j++) if (probs[j] > v0) { v0 = probs[j]; i0 = j; }
        int i1 = -1; float v1 = -1e30f;
#pragma unroll
        for (int j = 0; j < 8; j++) if (j != i0 && probs[j] > v1) { v1 = probs[j]; i1 = j; }
        float s = v0 + v1 + 1e-9f;
        node_top[2 * wid] = i0;  node_top[2 * wid + 1] = i1;
        node_gate[2 * wid] = v0 / s;  node_gate[2 * wid + 1] = v1 / s;
        conf[wid] = 1.f / (1.f + expf(-pc));
    }
}

__global__ void expert_hist_k(const int* __restrict__ node_top, int* __restrict__ ec) {
    __shared__ int h[NEXP];
    if (threadIdx.x < NEXP) h[threadIdx.x] = 0;
    __syncthreads();
    int i = blockIdx.x * 256 + threadIdx.x;
    if (i < NSLOT) atomicAdd(&h[node_top[i]], 1);
    __syncthreads();
    if (threadIdx.x < NEXP && h[threadIdx.x] > 0) atomicAdd(&ec[threadIdx.x], h[threadIdx.x]);
}

__global__ void expert_scan_k(const int* __restrict__ ec, int* __restrict__ es,
                              int* __restrict__ ecur) {
    if (blockIdx.x == 0 && threadIdx.x == 0) {
        int acc = 0;
        for (int e = 0; e < NEXP; e++) { es[e] = acc; acc += ec[e]; ecur[e] = 0; }
        es[NEXP] = acc;
    }
}

__global__ void fill_experts_k(const int* __restrict__ node_top, const float* __restrict__ node_gate,
                               const int* __restrict__ es, int* __restrict__ ecur,
                               int* __restrict__ slot_node, float* __restrict__ slot_gate,
                               int* __restrict__ node_slot) {
    __shared__ int hcnt[NEXP], hbase[NEXP];
    int tid = threadIdx.x;
    if (tid < NEXP) hcnt[tid] = 0;
    __syncthreads();
    int i = blockIdx.x * 256 + tid;
    int e = 0, local = 0;
    bool act = (i < NSLOT);
    if (act) {
        e = node_top[i];
        local = atomicAdd(&hcnt[e], 1);
    }
    __syncthreads();
    if (tid < NEXP) hbase[tid] = (hcnt[tid] > 0) ? atomicAdd(&ecur[tid], hcnt[tid]) : 0;
    __syncthreads();
    if (act) {
        int slot = es[e] + hbase[e] + local;
        slot_node[slot] = i >> 1;
        slot_gate[slot] = node_gate[i];
        node_slot[i] = slot;
    }
}

__global__ void combine_k(const float* __restrict__ expout, const float* __restrict__ weak,
                          const float* __restrict__ conf, const int* __restrict__ node_slot,
                          float* __restrict__ r) {
    int gid = blockIdx.x * 256 + threadIdx.x;
    if (gid >= NN * (D / 4)) return;
    int n = gid >> 6, c4 = gid & 63;
    int s0 = node_slot[2 * n], s1 = node_slot[2 * n + 1];
    float4 e0 = reinterpret_cast<const float4*>(expout + (size_t)s0 * D)[c4];
    float4 e1 = reinterpret_cast<const float4*>(expout + (size_t)s1 * D)[c4];
    float4 w  = reinterpret_cast<const float4*>(weak + (size_t)n * D)[c4];
    float cf = conf[n], cg = 1.f - cf;
    float4 o;
    o.x = fmaxf(cf * (e0.x + e1.x) + cg * w.x, 0.f);
    o.y = fmaxf(cf * (e0.y + e1.y) + cg * w.y, 0.f);
    o.z = fmaxf(cf * (e0.z + e1.z) + cg * w.z, 0.f);
    o.w = fmaxf(cf * (e0.w + e1.w) + cg * w.w, 0.f);
    reinterpret_cast<float4*>(r + (size_t)n * RD)[c4] = o;
}

// ---------------------------------------------------------------------------
// weight -> fragment-ready tiled bf16x3 planes.
// src: nm matrices [K][N] f32. dst planes: [nm][N/32][K/16][64][8] u16 where
// tile (mat,nb,kb), lane l, elem j holds B[kb*16 + (l>>5)*8 + j][nb*32 + (l&31)].
// A wave's B-fragment load is then one coalesced 1KB global_load_dwordx4.
// ---------------------------------------------------------------------------
__global__ void btile_k(const float* __restrict__ src, u16* __restrict__ dH,
                        u16* __restrict__ dM, u16* __restrict__ dL,
                        int K, int N, int total) {
    int gid = blockIdx.x * 256 + threadIdx.x;
    if (gid >= total) return;                  // total = nm*(N/32)*(K/16)*64
    int l = gid & 63;
    int tile = gid >> 6;
    int K16 = K >> 4;
    int kb = tile % K16;
    int t2 = tile / K16;
    int N32 = N >> 5;
    int nb = t2 % N32;
    int mat = t2 / N32;
    int kbase = (kb << 4) + ((l >> 5) << 3);
    int n = (nb << 5) + (l & 31);
    const float* s = src + ((size_t)mat * K + kbase) * N + n;
    short8v vh, vm, vl;
#pragma unroll
    for (int j = 0; j < 8; j++) {
        u16 hh, mm, ll;
        split1(s[(size_t)j * N], hh, mm, ll);
        vh[j] = (short)hh; vm[j] = (short)mm; vl[j] = (short)ll;
    }
    size_t o = (size_t)gid * 8;
    *reinterpret_cast<short8v*>(dH + o) = vh;
    *reinterpret_cast<short8v*>(dM + o) = vm;
    *reinterpret_cast<short8v*>(dL + o) = vl;
}

// ---------------------------------------------------------------------------
// bf16x3 split MFMA GEMM: C[M,N] = A[M,K] * B[K,N], f32-accurate (~2^-25).
// A: f32, split on the fly during LDS staging (BK=16, 18.4 KB LDS).
// B: fragment-tiled bf16 planes, loaded global->reg (coalesced, L2-resident).
// 128x128 block tile, 4 waves of 64x64 (2x2 frags of 32x32x16).
// MODE 0: plain rows; MODE 1: rows gathered via slot_node, +bias, relu;
// MODE 2: rows are slots, +bias, *gate.
// ---------------------------------------------------------------------------
template <int MODE>
__global__ __launch_bounds__(256, 3) void gemm_mfma(
    const float* __restrict__ A, int lda,
    const u16* __restrict__ BH, const u16* __restrict__ BM,
    const u16* __restrict__ BL,
    const float* __restrict__ bias,
    float* __restrict__ C, int ldc,
    const int* __restrict__ es,
    const int* __restrict__ slot_node,
    const float* __restrict__ slot_gate,
    int M, int N, int K) {
    constexpr int LDK2 = 24;                 // padded row stride (u16 elems)
    constexpr int PL2 = 128 * LDK2;          // one plane (elems)
    __shared__ u16 sA[3 * PL2];              // 18,432 B

    int tid = threadIdx.x;
    int row0, valid_rows;
    if (MODE == 0) {
        row0 = blockIdx.x * 128;
        valid_rows = M - row0; if (valid_rows > 128) valid_rows = 128;
    } else {
        int bx = blockIdx.x, acc0 = 0, expert = -1, mt = 0;
        row0 = 0; valid_rows = 0;
        for (int e = 0; e < NEXP; e++) {
            int c = es[e + 1] - es[e];
            int t = (c + 127) >> 7;
            if (bx < acc0 + t) {
                expert = e; mt = bx - acc0; row0 = es[e] + (mt << 7);
                valid_rows = c - (mt << 7); if (valid_rows > 128) valid_rows = 128;
                break;
            }
            acc0 += t;
        }
        if (expert < 0) return;
        size_t bo = (size_t)expert * N * K;  // per-matrix plane stride
        BH += bo; BM += bo; BL += bo;
        bias += expert * D;
    }
    int ncol0 = blockIdx.y * 128;

    // A staging coords: 2 threads per row; each covers 8 k (one short8v/plane)
    int srow = tid >> 1;
    int koff = (tid & 1) * 8;
    int grow;
    {
        int i0 = row0 + srow;
        if (MODE == 1) {
            i0 = i0 < NSLOT ? i0 : NSLOT - 1;
            grow = slot_node[i0];
        } else {
            grow = i0 < M ? i0 : M - 1;
        }
    }
    const float* pA = A + (size_t)grow * lda + koff;

    // fragment coords
    int lane = tid & 63;
    int wr = ((tid >> 7) & 1) * 64;   // wave row offset
    int wc = ((tid >> 6) & 1) * 64;   // wave col offset
    int fl = lane & 31;
    int fh8 = (lane >> 5) * 8;
    int K16 = K >> 4;
    int nb0 = (ncol0 + wc) >> 5;
    size_t tb0 = ((size_t)nb0 * K16) * 512 + (size_t)lane * 8;
    size_t tb1 = ((size_t)(nb0 + 1) * K16) * 512 + (size_t)lane * 8;

    f32x16 acc[2][2] = {};
    int aoff = srow * LDK2 + koff;
    const u16* Af0 = sA + (wr + fl) * LDK2 + fh8;
    const u16* Af1 = Af0 + 32 * LDK2;

    for (int kt = 0; kt < K; kt += 16) {
        // issue global loads early: A rows (f32) + 6 B fragments (coalesced 1KB)
        float4 av0 = *reinterpret_cast<const float4*>(pA + kt);
        float4 av1 = *reinterpret_cast<const float4*>(pA + kt + 4);
        size_t o0 = tb0 + (size_t)(kt >> 4) * 512;
        size_t o1 = tb1 + (size_t)(kt >> 4) * 512;
        short8v bH0 = *reinterpret_cast<const short8v*>(BH + o0);
        short8v bM0 = *reinterpret_cast<const short8v*>(BM + o0);
        short8v bL0 = *reinterpret_cast<const short8v*>(BL + o0);
        short8v bH1 = *reinterpret_cast<const short8v*>(BH + o1);
        short8v bM1 = *reinterpret_cast<const short8v*>(BM + o1);
        short8v bL1 = *reinterpret_cast<const short8v*>(BL + o1);
        __syncthreads();
        {
            short8v h, m, l;
            split8(av0, av1, h, m, l);
            *reinterpret_cast<short8v*>(&sA[0 * PL2 + aoff]) = h;
            *reinterpret_cast<short8v*>(&sA[1 * PL2 + aoff]) = m;
            *reinterpret_cast<short8v*>(&sA[2 * PL2 + aoff]) = l;
        }
        __syncthreads();
        short8v aH0 = *reinterpret_cast<const short8v*>(Af0);
        short8v aM0 = *reinterpret_cast<const short8v*>(Af0 + PL2);
        short8v aL0 = *reinterpret_cast<const short8v*>(Af0 + 2 * PL2);
        short8v aH1 = *reinterpret_cast<const short8v*>(Af1);
        short8v aM1 = *reinterpret_cast<const short8v*>(Af1 + PL2);
        short8v aL1 = *reinterpret_cast<const short8v*>(Af1 + 2 * PL2);
#define MFMA_ACC(d, a, b) d = __builtin_amdgcn_mfma_f32_32x32x16_bf16(a, b, d, 0, 0, 0)
        MFMA_ACC(acc[0][0], aH0, bH0); MFMA_ACC(acc[0][0], aH0, bM0);
        MFMA_ACC(acc[0][0], aM0, bH0); MFMA_ACC(acc[0][0], aH0, bL0);
        MFMA_ACC(acc[0][0], aM0, bM0); MFMA_ACC(acc[0][0], aL0, bH0);
        MFMA_ACC(acc[0][1], aH0, bH1); MFMA_ACC(acc[0][1], aH0, bM1);
        MFMA_ACC(acc[0][1], aM0, bH1); MFMA_ACC(acc[0][1], aH0, bL1);
        MFMA_ACC(acc[0][1], aM0, bM1); MFMA_ACC(acc[0][1], aL0, bH1);
        MFMA_ACC(acc[1][0], aH1, bH0); MFMA_ACC(acc[1][0], aH1, bM0);
        MFMA_ACC(acc[1][0], aM1, bH0); MFMA_ACC(acc[1][0], aH1, bL0);
        MFMA_ACC(acc[1][0], aM1, bM0); MFMA_ACC(acc[1][0], aL1, bH0);
        MFMA_ACC(acc[1][1], aH1, bH1); MFMA_ACC(acc[1][1], aH1, bM1);
        MFMA_ACC(acc[1][1], aM1, bH1); MFMA_ACC(acc[1][1], aH1, bL1);
        MFMA_ACC(acc[1][1], aM1, bM1); MFMA_ACC(acc[1][1], aL1, bH1);
#undef MFMA_ACC
    }

    // epilogue: C/D layout col=lane&31, row=(reg&3)+8*(reg>>2)+4*(lane>>5)
    int fh = lane >> 5;
#pragma unroll
    for (int i = 0; i < 2; i++) {
#pragma unroll
        for (int j = 0; j < 2; j++) {
            int colg = ncol0 + wc + j * 32 + fl;
            float bv = (MODE != 0) ? bias[colg] : 0.f;
#pragma unroll
            for (int rg = 0; rg < 16; rg++) {
                int lrow = wr + i * 32 + (rg & 3) + 8 * (rg >> 2) + 4 * fh;
                if (lrow >= valid_rows) continue;
                int growo = row0 + lrow;
                float v = acc[i][j][rg] + bv;
                if (MODE == 1) {
                    v = fmaxf(v, 0.f);
                } else if (MODE == 2) {
                    v *= slot_gate[growo];
                }
                C[(size_t)growo * ldc + colg] = v;
            }
        }
    }
}

// ---------------------------------------------------------------------------
extern "C" void kernel_launch(void* const* d_in, const int* in_sizes, int n_in,
                              void* d_out, int out_size, void* d_ws, size_t ws_size,
                              hipStream_t stream) {
    (void)in_sizes; (void)n_in; (void)out_size; (void)ws_size;
    const float* x    = (const float*)d_in[0];
    const int*   ei   = (const int*)d_in[1];
    const float* Wg   = (const float*)d_in[2];
    const float* We   = (const float*)d_in[3];
    const float* Ww   = (const float*)d_in[4];
    const float* W1   = (const float*)d_in[5];
    const float* b1   = (const float*)d_in[6];
    const float* W2   = (const float*)d_in[7];
    const float* b2   = (const float*)d_in[8];
    const float* wcp  = (const float*)d_in[9];
    const float* Wout = (const float*)d_in[10];
    float* out = (float*)d_out;

    char* p = (char*)d_ws;
    auto alloc = [&](size_t bytes) -> char* {
        char* q = p; p += (bytes + 255) & ~(size_t)255; return q;
    };
    int*   cnt       = (int*)alloc((size_t)NN * 4);
    int*   row_start = (int*)alloc((size_t)(NN + 1) * 4);
    int*   cur       = (int*)alloc((size_t)NN * 4);
    int*   bsum      = (int*)alloc(128 * 4);
    int*   csr_src   = (int*)alloc((size_t)NEDGE * 4);
    float* r         = (float*)alloc((size_t)NN * RD * 4);
    float* hid       = (float*)alloc((size_t)NSLOT * D * 4);   // weak aliases rows 0..NN-1 after GEMM2
    float* expout    = (float*)alloc((size_t)NSLOT * D * 4);
    float* conf      = (float*)alloc((size_t)NN * 4);
    int*   node_top  = (int*)alloc((size_t)2 * NN * 4);
    float* node_gate = (float*)alloc((size_t)2 * NN * 4);
    int*   node_slot = (int*)alloc((size_t)2 * NN * 4);
    int*   slot_node = (int*)alloc((size_t)NSLOT * 4);
    float* slot_gate = (float*)alloc((size_t)NSLOT * 4);
    int*   ec        = (int*)alloc(64 * 4);
    int*   es        = (int*)alloc(64 * 4);
    int*   ecur      = (int*)alloc(64 * 4);
    // per-layer weight planes (fragment-tiled bf16 x 3)
    u16* w1tH = (u16*)alloc((size_t)NEXP * D * RD * 2);
    u16* w1tM = (u16*)alloc((size_t)NEXP * D * RD * 2);
    u16* w1tL = (u16*)alloc((size_t)NEXP * D * RD * 2);
    u16* w2tH = (u16*)alloc((size_t)NEXP * D * D * 2);
    u16* w2tM = (u16*)alloc((size_t)NEXP * D * D * 2);
    u16* w2tL = (u16*)alloc((size_t)NEXP * D * D * 2);
    u16* wwtH = (u16*)alloc((size_t)D * RD * 2);
    u16* wwtM = (u16*)alloc((size_t)D * RD * 2);
    u16* wwtL = (u16*)alloc((size_t)D * RD * 2);
    u16* wotH = (u16*)alloc((size_t)OD * D * 2);
    u16* wotM = (u16*)alloc((size_t)OD * D * 2);
    u16* wotL = (u16*)alloc((size_t)OD * D * 2);
    float* weak = hid;   // alias: hid is dead when weak GEMM runs

    const int* srcp = ei;
    const int* dstp = ei + NEDGE;
    const int EB = (NEDGE + 255) / 256;

    // graph prep (once per launch)
    copy_x_zero_cnt_k<<<5000, 256, 0, stream>>>(x, r, cnt);
    count_edges_k<<<EB, 256, 0, stream>>>(dstp, cnt);
    block_sums_k<<<NODE_BLOCKS, 256, 0, stream>>>(cnt, bsum);
    scan_bsums_k<<<1, 64, 0, stream>>>(bsum, row_start);
    block_scan_k<<<NODE_BLOCKS, 256, 0, stream>>>(cnt, bsum, row_start, cur);
    fill_csr_k<<<EB, 256, 0, stream>>>(srcp, dstp, cur, csr_src);
    // Wout planes (once): total = 1*(128/32)*(256/16)*64 = 4096
    btile_k<<<16, 256, 0, stream>>>(Wout, wotH, wotM, wotL, D, OD, 4096);

    for (int l = 0; l < 3; l++) {
        // weight planes for this layer (fragment-tiled)
        btile_k<<<512, 256, 0, stream>>>(W1 + (size_t)l * NEXP * RD * D,
                                         w1tH, w1tM, w1tL, RD, D, 131072);
        btile_k<<<256, 256, 0, stream>>>(W2 + (size_t)l * NEXP * D * D,
                                         w2tH, w2tM, w2tL, D, D, 65536);
        btile_k<<<64, 256, 0, stream>>>(Ww + (size_t)l * RD * D,
                                        wwtH, wwtM, wwtL, RD, D, 16384);
        aggregate_k<<<5000, 256, 0, stream>>>(r, row_start, csr_src, ec);
        router_k<<<5000, 256, 0, stream>>>(r,
            Wg + (size_t)l * RD * 4, We + (size_t)l * RD * 8, wcp + (size_t)l * RD,
            node_top, node_gate, conf);
        expert_hist_k<<<ASSIGN_BLOCKS, 256, 0, stream>>>(node_top, ec);
        expert_scan_k<<<1, 64, 0, stream>>>(ec, es, ecur);
        fill_experts_k<<<ASSIGN_BLOCKS, 256, 0, stream>>>(node_top, node_gate, es, ecur,
                                                          slot_node, slot_gate, node_slot);
        // hid[slot] = relu(r[node] @ W1[e] + b1[e])
        gemm_mfma<1><<<dim3(320, 2), 256, 0, stream>>>(r, RD, w1tH, w1tM, w1tL,
            b1 + (size_t)l * NEXP * D, hid, D, es, slot_node, slot_gate, NSLOT, D, RD);
        // expout[slot] = (hid[slot] @ W2[e] + b2[e]) * gate[slot]
        gemm_mfma<2><<<dim3(320, 2), 256, 0, stream>>>(hid, D, w2tH, w2tM, w2tL,
            b2 + (size_t)l * NEXP * D, expout, D, es, slot_node, slot_gate, NSLOT, D, D);
        // weak = r @ Ww  (writes over hid rows 0..NN-1, safe: hid consumed)
        gemm_mfma<0><<<dim3(157, 2), 256, 0, stream>>>(r, RD, wwtH, wwtM, wwtL,
            nullptr, weak, D, nullptr, nullptr, nullptr, NN, D, RD);
        combine_k<<<5000, 256, 0, stream>>>(expout, weak, conf, node_slot, r);
    }
    // out = h @ Wout  (h = r[:, :256], so K=256 over lda=512)
    gemm_mfma<0><<<dim3(157, 1), 256, 0, stream>>>(r, RD, wotH, wotM, wotL,
        nullptr, out, OD, nullptr, nullptr, nullptr, NN, OD, D);
}